// Round 4
// baseline (502.151 us; speedup 1.0000x reference)
//
#include <hip/hip_runtime.h>

#define N_NODES 100000
#define N_EDGES 3200000
#define R_REL   8
#define C_IN    128
#define HID     64
#define WCOLS   576   // 8 relations * 64 + 64 (root slot)

// counting-sort parameters
#define NBUCK 500     // dst buckets
#define NPB   200     // nodes per bucket (500*200 = N)
#define NBLK  256     // edge chunks (long runs: CHUNK/NBUCK = 25 edges = 100 B)
#define CHUNK 12500   // E / NBLK (exact)
#define NCELL (NBUCK * NBLK)   // 128000
#define BCAP  7680    // LDS staging capacity per bucket (mean 6400, sigma ~80)

typedef __attribute__((ext_vector_type(8))) short  short8;
typedef __attribute__((ext_vector_type(4))) float  float4v;

__device__ __forceinline__ float bf2f(unsigned short u) {
    union { unsigned int i; float f; } v; v.i = ((unsigned int)u) << 16; return v.f;
}
__device__ __forceinline__ unsigned short f2bf(float f) {
    union { float f; unsigned int i; } v; v.f = f;
    unsigned int r = v.i + 0x7FFFu + ((v.i >> 16) & 1u);   // RNE
    return (unsigned short)(r >> 16);
}
__device__ __forceinline__ float rl_f(float v, int j) {
    union { float f; int i; } a, b; a.f = v;
    b.i = __builtin_amdgcn_readlane(a.i, j);
    return b.f;
}

// ---------------- weight prep (f32 -> bf16) ----------------------------------
// BT1:  [576 cols][128 k]  for gemm_rows (layer-1 transform-then-gather)
// BT2b: [64  cols][576 k]  for gemm_out  (layer-2 aggregate-then-transform):
//       k<512: W2[k>>6][k&63][col] (stacked relations), k>=512: root2[k-512][col]
__global__ void prep_wcat(const float* __restrict__ W1,
                          const float* __restrict__ root1,
                          const float* __restrict__ W2,
                          const float* __restrict__ root2,
                          unsigned short* __restrict__ BT1,
                          unsigned short* __restrict__ BT2b) {
    int idx = blockIdx.x * 256 + threadIdx.x;
    const int T1 = WCOLS * C_IN;          // 73728
    const int T2 = 64 * WCOLS;            // 36864
    if (idx < T1) {
        int c = idx / C_IN, k = idx % C_IN;
        float v;
        if (c < 512) { int r = c >> 6, h = c & 63; v = W1[r * (C_IN * 64) + k * 64 + h]; }
        else         { v = root1[k * 64 + (c - 512)]; }
        BT1[idx] = f2bf(v);
    } else if (idx < T1 + T2) {
        int j = idx - T1;
        int c2 = j / WCOLS, k2 = j % WCOLS;
        float v;
        if (k2 < 512) { int r = k2 >> 6, ch = k2 & 63; v = W2[r * (HID * 64) + ch * 64 + c2]; }
        else          { v = root2[(k2 - 512) * 64 + c2]; }
        BT2b[j] = f2bf(v);
    }
}

// ---------------- K1: per-block LDS counting sort, sequential writes ---------
__global__ __launch_bounds__(512)
void edge_sort_local(const int* __restrict__ src, const int* __restrict__ dst,
                     const int* __restrict__ et,
                     unsigned int* __restrict__ esort,
                     int* __restrict__ bcountT, int* __restrict__ lstartT) {
    __shared__ int cnt[NBUCK], cur[NBUCK], tsum[512];
    __shared__ unsigned int sedge[CHUNK];               // 50 KB
    const int blk = blockIdx.x, tid = threadIdx.x;
    const int e0 = blk * CHUNK;

    for (int i = tid; i < NBUCK; i += 512) cnt[i] = 0;
    __syncthreads();
    for (int i = tid; i < CHUNK; i += 512)
        atomicAdd(&cnt[dst[e0 + i] / NPB], 1);
    __syncthreads();

    int v = (tid < NBUCK) ? cnt[tid] : 0;
    tsum[tid] = v; __syncthreads();
    for (int off = 1; off < 512; off <<= 1) {
        int t = (tid >= off) ? tsum[tid - off] : 0;
        __syncthreads(); tsum[tid] += t; __syncthreads();
    }
    if (tid < NBUCK) cur[tid] = tsum[tid] - v;
    __syncthreads();

    for (int b = tid; b < NBUCK; b += 512) {
        bcountT[blk * NBUCK + b] = cnt[b];
        lstartT[blk * NBUCK + b] = cur[b];
    }
    __syncthreads();

    for (int i = tid; i < CHUNK; i += 512) {
        int d = dst[e0 + i];
        int b = d / NPB;
        int pos = atomicAdd(&cur[b], 1);
        sedge[pos] = ((unsigned int)src[e0 + i] << 11) |
                     ((unsigned int)(d - b * NPB) << 3) | (unsigned int)et[e0 + i];
    }
    __syncthreads();
    for (int i = tid; i < CHUNK; i += 512) esort[e0 + i] = sedge[i];
}

// ---------------- bucket totals + scan over 500 buckets ----------------------
__global__ __launch_bounds__(256)
void btot_sum(const int* __restrict__ bcountT, int* __restrict__ btot) {
    __shared__ int tsum[256];
    const int b = blockIdx.x, tid = threadIdx.x;
    int s = 0;
    for (int blk = tid; blk < NBLK; blk += 256) s += bcountT[blk * NBUCK + b];
    tsum[tid] = s; __syncthreads();
    for (int off = 128; off > 0; off >>= 1) {
        if (tid < off) tsum[tid] += tsum[tid + off];
        __syncthreads();
    }
    if (tid == 0) btot[b] = tsum[0];
}

__global__ __launch_bounds__(512)
void scan_btot(int* __restrict__ btot, int nb) {   // nb <= 512, exclusive in place
    __shared__ int tmp[512];
    int tid = threadIdx.x;
    int v = (tid < nb) ? btot[tid] : 0;
    tmp[tid] = v; __syncthreads();
    for (int off = 1; off < 512; off <<= 1) {
        int t = (tid >= off) ? tmp[tid - off] : 0;
        __syncthreads(); tmp[tid] += t; __syncthreads();
    }
    if (tid < nb) btot[tid] = tmp[tid] - v;
}

// ---------------- bucket_build v5: LDS-staged CSR emit, elist = src ----------
// emits elist[p] = src node index (relation implicit via rowstart8 segments)
// and per-(node,rel) boundary table rowstart8[n*8+r].
__global__ __launch_bounds__(512)
void bucket_build(const unsigned int* __restrict__ esort,
                  const int* __restrict__ bcountT, const int* __restrict__ lstartT,
                  const int* __restrict__ btot,
                  unsigned int* __restrict__ elist,
                  int* __restrict__ rowstart8) {
    __shared__ int   cnt[2048], cur[2048], tsum[512];   // 8192+8192+2048 B
    __shared__ int   rlen[NBLK], rpos[NBLK], rloff[NBLK]; // 3072 B
    __shared__ unsigned int sedge[BCAP];                // 30720 B
    __shared__ unsigned int selist[BCAP];               // 30720 B  (total ~83 KB)

    const int b = blockIdx.x, tid = threadIdx.x;
    const int seg0 = btot[b];

    for (int i = tid; i < 2048; i += 512) cnt[i] = 0;
    if (tid < NBLK) {
        rlen[tid] = bcountT[tid * NBUCK + b];
        rpos[tid] = tid * CHUNK + lstartT[tid * NBUCK + b];
    }
    __syncthreads();

    int rv = (tid < NBLK) ? rlen[tid] : 0;
    tsum[tid] = rv; __syncthreads();
    for (int off = 1; off < 512; off <<= 1) {
        int t = (tid >= off) ? tsum[tid - off] : 0;
        __syncthreads(); tsum[tid] += t; __syncthreads();
    }
    if (tid < NBLK) rloff[tid] = tsum[tid] - rv;
    const int total = tsum[NBLK - 1];       // bucket edge count
    __syncthreads();
    const bool fits = (total <= BCAP);      // safety fallback

    // ---- pass 1: flat stage + histogram (esort read once) ----
    for (int i = tid; i < total; i += 512) {
        int lo = 0, hi = NBLK - 1;          // largest blk with rloff[blk] <= i
        while (lo < hi) { int mid = (lo + hi + 1) >> 1; if (rloff[mid] <= i) lo = mid; else hi = mid - 1; }
        unsigned int e = esort[rpos[lo] + (i - rloff[lo])];
        if (fits) sedge[i] = e;
        atomicAdd(&cnt[(int)((e >> 3) & 255u) * 8 + (int)(e & 7u)], 1);
    }
    __syncthreads();

    // ---- exclusive scan over 2048 counters ----
    int base = tid * 4, s = 0, loc[4];
#pragma unroll
    for (int k = 0; k < 4; ++k) { loc[k] = s; s += cnt[base + k]; }
    tsum[tid] = s; __syncthreads();
    for (int off = 1; off < 512; off <<= 1) {
        int t = (tid >= off) ? tsum[tid - off] : 0;
        __syncthreads(); tsum[tid] += t; __syncthreads();
    }
    int texcl = tsum[tid] - s;
#pragma unroll
    for (int k = 0; k < 4; ++k) cur[base + k] = texcl + loc[k];
    __syncthreads();

    for (int i = tid; i < NPB * 8; i += 512)
        rowstart8[(b * NPB) * 8 + i] = seg0 + cur[i];
    if (b == NBUCK - 1 && tid == 0) rowstart8[N_NODES * 8] = N_EDGES;
    __syncthreads();

    // ---- pass 2: flat emit into LDS (scatter stays on-chip) ----
    for (int i = tid; i < total; i += 512) {
        unsigned int e;
        if (fits) e = sedge[i];
        else {
            int lo = 0, hi = NBLK - 1;
            while (lo < hi) { int mid = (lo + hi + 1) >> 1; if (rloff[mid] <= i) lo = mid; else hi = mid - 1; }
            e = esort[rpos[lo] + (i - rloff[lo])];
        }
        int r = (int)(e & 7u);
        int j = (int)((e >> 3) & 255u) * 8 + r;
        int p = atomicAdd(&cur[j], 1);
        unsigned int src = e >> 11;
        if (fits) selist[p] = src;
        else      elist[seg0 + p] = src;
    }
    __syncthreads();

    if (fits) {
        for (int i = tid; i < total; i += 512)
            elist[seg0 + i] = selist[i];
    }
}

// ---------------- GEMM: Out[N][576] (bf16) = A[N][K] @ Wcat ------------------
template <int K, bool AF32>
__global__ __launch_bounds__(256)
void gemm_rows(const void* __restrict__ Araw,
               const unsigned short* __restrict__ BT,
               unsigned short* __restrict__ Out, int nrows) {
    constexpr int KSTEPS = K / 32;
    constexpr int LDB = K + 8;
    __shared__ __align__(16) unsigned short Blds[64 * LDB];
    __shared__ __align__(16) unsigned short stage[4][16 * 64];

    const int wave = threadIdx.x >> 6;
    const int lane = threadIdx.x & 63;
    const int l15 = lane & 15, quad = lane >> 4;
    const int rowbase = blockIdx.x * 64 + wave * 16;
    int arow = rowbase + l15;
    if (arow >= nrows) arow = nrows - 1;

    short8 afrag[KSTEPS];
    if constexpr (AF32) {
        const float* Af = (const float*)Araw;
#pragma unroll
        for (int ks = 0; ks < KSTEPS; ++ks) {
            const float* p = Af + (size_t)arow * K + ks * 32 + quad * 8;
            float4v u0 = *(const float4v*)p;
            float4v u1 = *(const float4v*)(p + 4);
            short8 f;
            f[0] = (short)f2bf(u0[0]); f[1] = (short)f2bf(u0[1]);
            f[2] = (short)f2bf(u0[2]); f[3] = (short)f2bf(u0[3]);
            f[4] = (short)f2bf(u1[0]); f[5] = (short)f2bf(u1[1]);
            f[6] = (short)f2bf(u1[2]); f[7] = (short)f2bf(u1[3]);
            afrag[ks] = f;
        }
    } else {
        const unsigned short* Ab = (const unsigned short*)Araw;
#pragma unroll
        for (int ks = 0; ks < KSTEPS; ++ks)
            afrag[ks] = *(const short8*)(Ab + (size_t)arow * K + ks * 32 + quad * 8);
    }

    for (int chunk = 0; chunk < 9; ++chunk) {
        __syncthreads();
        {
            const unsigned short* src = BT + (size_t)chunk * 64 * K;
            const int nvec = 64 * K / 8;
            for (int i = threadIdx.x; i < nvec; i += 256) {
                int r = i / (K / 8);
                int cpos = (i % (K / 8)) * 8;
                *(uint4*)(&Blds[r * LDB + cpos]) = *(const uint4*)(src + r * K + cpos);
            }
        }
        __syncthreads();

        float4v acc[4];
#pragma unroll
        for (int ct = 0; ct < 4; ++ct) { acc[ct][0] = 0.f; acc[ct][1] = 0.f; acc[ct][2] = 0.f; acc[ct][3] = 0.f; }

#pragma unroll
        for (int ct = 0; ct < 4; ++ct) {
#pragma unroll
            for (int ks = 0; ks < KSTEPS; ++ks) {
                short8 bfrag = *(const short8*)(&Blds[(ct * 16 + l15) * LDB + ks * 32 + quad * 8]);
                acc[ct] = __builtin_amdgcn_mfma_f32_16x16x32_bf16(afrag[ks], bfrag, acc[ct], 0, 0, 0);
            }
        }

#pragma unroll
        for (int ct = 0; ct < 4; ++ct)
#pragma unroll
            for (int r = 0; r < 4; ++r)
                stage[wave][(quad * 4 + r) * 64 + ct * 16 + l15] = f2bf(acc[ct][r]);
        __syncthreads();

        {
            int r = lane >> 2, j = lane & 3;
            int orow = rowbase + r;
            if (orow < nrows) {
#pragma unroll
                for (int p = 0; p < 2; ++p) {
                    int c0 = (j + p * 4) * 8;
                    uint4 v = *(const uint4*)&stage[wave][r * 64 + c0];
                    *(uint4*)(Out + (size_t)orow * WCOLS + chunk * 64 + c0) = v;
                }
            }
        }
    }
}

// ---------------- gemm_out: Out[N][64] (f32) = A[N][576] @ BT2b^T + bias -----
// B (64x576 = 73.7 KB) fits LDS entirely; loaded once. A streamed from global.
__global__ __launch_bounds__(256)
void gemm_out(const unsigned short* __restrict__ A,     // [N][576] bf16
              const unsigned short* __restrict__ BT,    // [64][576] bf16
              const float* __restrict__ bias,
              float* __restrict__ Out, int nrows) {
    constexpr int K = WCOLS;            // 576
    constexpr int LDB = K + 8;          // 584 shorts (1168 B, 16B-aligned rows)
    __shared__ __align__(16) unsigned short Blds[64 * LDB];   // 74.8 KB

    const int wave = threadIdx.x >> 6;
    const int lane = threadIdx.x & 63;
    const int l15 = lane & 15, quad = lane >> 4;
    const int rowbase = blockIdx.x * 64 + wave * 16;
    int arow = rowbase + l15;
    if (arow >= nrows) arow = nrows - 1;

    {
        const int nvec = 64 * K / 8;    // 4608
        for (int i = threadIdx.x; i < nvec; i += 256) {
            int r = i / (K / 8);        // output col
            int c = (i % (K / 8)) * 8;
            *(uint4*)(&Blds[r * LDB + c]) = *(const uint4*)(BT + r * K + c);
        }
    }
    __syncthreads();

    float4v acc[4];
#pragma unroll
    for (int ct = 0; ct < 4; ++ct) { acc[ct][0] = 0.f; acc[ct][1] = 0.f; acc[ct][2] = 0.f; acc[ct][3] = 0.f; }

    const unsigned short* Ar = A + (size_t)arow * K;
#pragma unroll
    for (int ks = 0; ks < K / 32; ++ks) {     // 18
        short8 afrag = *(const short8*)(Ar + ks * 32 + quad * 8);
#pragma unroll
        for (int ct = 0; ct < 4; ++ct) {
            short8 bfrag = *(const short8*)(&Blds[(ct * 16 + l15) * LDB + ks * 32 + quad * 8]);
            acc[ct] = __builtin_amdgcn_mfma_f32_16x16x32_bf16(afrag, bfrag, acc[ct], 0, 0, 0);
        }
    }

#pragma unroll
    for (int ct = 0; ct < 4; ++ct) {
        int c = ct * 16 + l15;
        float bv = bias[c];
#pragma unroll
        for (int r = 0; r < 4; ++r) {
            int orow = rowbase + quad * 4 + r;
            if (orow < nrows)
                Out[(size_t)orow * 64 + c] = acc[ct][r] + bv;
        }
    }
}

// ---------------- layer-1 fused CSR aggregate + root + bias + relu -----------
// one wave per node, lane = channel. 16-deep explicit gather pipeline.
// elist = src; per-lane relation index derived from segment boundaries.
__global__ __launch_bounds__(256)
void agg_fused(const unsigned short* __restrict__ XW,
               const unsigned int* __restrict__ elist,
               const int* __restrict__ rowstart8,
               const float* __restrict__ bias,
               unsigned short* __restrict__ outp) {
    const int wave = threadIdx.x >> 6, lane = threadIdx.x & 63;
    const int n = blockIdx.x * 4 + wave;          // grid covers N exactly
    int r9 = 0;
    if (lane < 9) r9 = rowstart8[n * 8 + lane];
    const int b0 = __builtin_amdgcn_readlane(r9, 0);
    const int b1 = __builtin_amdgcn_readlane(r9, 1);
    const int b2 = __builtin_amdgcn_readlane(r9, 2);
    const int b3 = __builtin_amdgcn_readlane(r9, 3);
    const int b4 = __builtin_amdgcn_readlane(r9, 4);
    const int b5 = __builtin_amdgcn_readlane(r9, 5);
    const int b6 = __builtin_amdgcn_readlane(r9, 6);
    const int b7 = __builtin_amdgcn_readlane(r9, 7);
    const int b8 = __builtin_amdgcn_readlane(r9, 8);
    const int beg = b0, end = b8;

    auto invlen = [](int a, int bnd) {
        int l = bnd - a; return 1.0f / (float)(l > 1 ? l : 1);
    };
    const float il0 = invlen(b0, b1), il1 = invlen(b1, b2);
    const float il2 = invlen(b2, b3), il3 = invlen(b3, b4);
    const float il4 = invlen(b4, b5), il5 = invlen(b5, b6);
    const float il6 = invlen(b6, b7), il7 = invlen(b7, b8);

    const unsigned short* XWl = XW + lane;        // fold lane offset into base

    float acc = 0.f;
    int i = beg;
    while (i < end) {
        int m = end - i; if (m > 64) m = 64;
        int idx = i + lane; if (idx >= end) idx = end - 1;
        unsigned int sb = elist[idx];             // src (coalesced, 1 load / 64 edges)
        // per-lane relation + weight from segment membership
        int rl = (idx >= b1) + (idx >= b2) + (idx >= b3) + (idx >= b4) +
                 (idx >= b5) + (idx >= b6) + (idx >= b7);
        unsigned int ub = (sb * 9u + (unsigned int)rl) << 6;   // src*576 + r*64
        float wb = il0;
        wb = (idx >= b1) ? il1 : wb;
        wb = (idx >= b2) ? il2 : wb;
        wb = (idx >= b3) ? il3 : wb;
        wb = (idx >= b4) ? il4 : wb;
        wb = (idx >= b5) ? il5 : wb;
        wb = (idx >= b6) ? il6 : wb;
        wb = (idx >= b7) ? il7 : wb;

        int j = 0;
        for (; j + 16 <= m; j += 16) {
            float vv[16], ww[16];
#pragma unroll
            for (int t = 0; t < 16; ++t) {
                unsigned int u = (unsigned int)__builtin_amdgcn_readlane((int)ub, j + t);
                ww[t] = rl_f(wb, j + t);
                vv[t] = bf2f(XWl[u]);
            }
#pragma unroll
            for (int t = 0; t < 16; ++t) acc += ww[t] * vv[t];
        }
        for (; j + 4 <= m; j += 4) {
            float vv[4], ww[4];
#pragma unroll
            for (int t = 0; t < 4; ++t) {
                unsigned int u = (unsigned int)__builtin_amdgcn_readlane((int)ub, j + t);
                ww[t] = rl_f(wb, j + t);
                vv[t] = bf2f(XWl[u]);
            }
#pragma unroll
            for (int t = 0; t < 4; ++t) acc += ww[t] * vv[t];
        }
        for (; j < m; ++j) {
            unsigned int u = (unsigned int)__builtin_amdgcn_readlane((int)ub, j);
            float w = rl_f(wb, j);
            acc += w * bf2f(XWl[u]);
        }
        i += m;
    }

    float res = acc + bf2f(XW[(size_t)n * WCOLS + 512 + lane]) + bias[lane];
    res = res > 0.f ? res : 0.f;
    outp[(size_t)n * 64 + lane] = f2bf(res);
}

// ---------------- layer-2 gather: agg[N][576] = per-rel means of h + h copy --
// gathers from h (12.8 MB, L2/LLC-resident) instead of hW (115 MB).
// per-relation segments unrolled -> static acc[8] indexing.
__global__ __launch_bounds__(256)
void agg_gather(const unsigned short* __restrict__ h,
                const unsigned int* __restrict__ elist,
                const int* __restrict__ rowstart8,
                unsigned short* __restrict__ agg) {
    const int wave = threadIdx.x >> 6, lane = threadIdx.x & 63;
    const int n = blockIdx.x * 4 + wave;
    int r9 = 0;
    if (lane < 9) r9 = rowstart8[n * 8 + lane];
    int bnd[9];
#pragma unroll
    for (int k = 0; k < 9; ++k) bnd[k] = __builtin_amdgcn_readlane(r9, k);

    const unsigned short* hl = h + lane;
    float acc[8];
#pragma unroll
    for (int r = 0; r < 8; ++r) acc[r] = 0.f;

#pragma unroll
    for (int r = 0; r < 8; ++r) {
        const int s0 = bnd[r], s1 = bnd[r + 1];
        int i = s0;
        while (i < s1) {
            int m = s1 - i; if (m > 64) m = 64;
            int idx = i + lane; if (idx >= s1) idx = s1 - 1;
            unsigned int ub = elist[idx] << 6;    // src*64 element offset
            int j = 0;
            for (; j + 4 <= m; j += 4) {
                float vv[4];
#pragma unroll
                for (int t = 0; t < 4; ++t) {
                    unsigned int u = (unsigned int)__builtin_amdgcn_readlane((int)ub, j + t);
                    vv[t] = bf2f(hl[u]);
                }
#pragma unroll
                for (int t = 0; t < 4; ++t) acc[r] += vv[t];
            }
            for (; j < m; ++j) {
                unsigned int u = (unsigned int)__builtin_amdgcn_readlane((int)ub, j);
                acc[r] += bf2f(hl[u]);
            }
            i += m;
        }
        int len = s1 - s0;
        acc[r] *= 1.0f / (float)(len > 1 ? len : 1);
    }

    unsigned short* arow = agg + (size_t)n * WCOLS;
#pragma unroll
    for (int r = 0; r < 8; ++r) arow[r * 64 + lane] = f2bf(acc[r]);
    arow[512 + lane] = h[(size_t)n * 64 + lane];
}

// ---------------- launch ------------------------------------------------------
extern "C" void kernel_launch(void* const* d_in, const int* in_sizes, int n_in,
                              void* d_out, int out_size, void* d_ws, size_t ws_size,
                              hipStream_t stream) {
    const float* x     = (const float*)d_in[0];
    const int*   eidx  = (const int*)d_in[1];
    const int*   etyp  = (const int*)d_in[2];
    const float* W1    = (const float*)d_in[3];
    const float* root1 = (const float*)d_in[4];
    const float* b1    = (const float*)d_in[5];
    const float* W2    = (const float*)d_in[6];
    const float* root2 = (const float*)d_in[7];
    const float* b2    = (const float*)d_in[8];
    float*       out   = (float*)d_out;

    char* ws = (char*)d_ws;
    size_t off = 0;
    auto alloc = [&](size_t bytes) { char* p = ws + off; off += (bytes + 255) & ~(size_t)255; return p; };

    unsigned short* xW       = (unsigned short*)alloc((size_t)N_NODES * WCOLS * 2); // 115.2 MB (reused as agg)
    unsigned short* h        = (unsigned short*)alloc((size_t)N_NODES * HID * 2);   //  12.8 MB
    unsigned int*   elist    = (unsigned int*)alloc((size_t)N_EDGES * 4);           //  12.8 MB
    int*            rowstart8= (int*)alloc(((size_t)N_NODES * 8 + 1) * 4);          //   3.2 MB
    unsigned short* BT1      = (unsigned short*)alloc((size_t)WCOLS * C_IN * 2);
    unsigned short* BT2b     = (unsigned short*)alloc((size_t)64 * WCOLS * 2);
    // total ~144.5 MB

    // sort scratch aliases into xW (dead before gemm1 writes xW)
    unsigned int* esort   = (unsigned int*)xW;                          // 12.8 MB
    int*          bcountT = (int*)((char*)xW + (size_t)N_EDGES * 4);    //  0.5 MB
    int*          lstartT = bcountT + NCELL;                            //  0.5 MB
    int*          btot    = lstartT + NCELL;                            //  2 KB

    const int* srcp = eidx;
    const int* dstp = eidx + N_EDGES;

    prep_wcat<<<(WCOLS * C_IN + 64 * WCOLS + 255) / 256, 256, 0, stream>>>(W1, root1, W2, root2, BT1, BT2b);

    // CSR build — sequential-write sort + fused per-bucket CSR emit
    edge_sort_local<<<NBLK, 512, 0, stream>>>(srcp, dstp, etyp, esort, bcountT, lstartT);
    btot_sum<<<NBUCK, 256, 0, stream>>>(bcountT, btot);
    scan_btot<<<1, 512, 0, stream>>>(btot, NBUCK);
    bucket_build<<<NBUCK, 512, 0, stream>>>(esort, bcountT, lstartT, btot, elist, rowstart8);

    const int gemm_grid = (N_NODES + 63) / 64;    // 1563
    const int agg_grid  = N_NODES / 4;            // 25000

    // layer 1: x (f32) -> xW (bf16) -> h (bf16, relu)  [transform-then-gather]
    gemm_rows<C_IN, true><<<gemm_grid, 256, 0, stream>>>((const void*)x, BT1, xW, N_NODES);
    agg_fused<<<agg_grid, 256, 0, stream>>>(xW, elist, rowstart8, b1, h);

    // layer 2: h -> agg[N][576] (reuse xW) -> out (f32)  [aggregate-then-transform]
    agg_gather<<<agg_grid, 256, 0, stream>>>(h, elist, rowstart8, xW);
    gemm_out<<<gemm_grid, 256, 0, stream>>>(xW, BT2b, b2, out, N_NODES);
}

// Round 5
// 410.967 us; speedup vs baseline: 1.2219x; 1.2219x over previous
//
#include <hip/hip_runtime.h>

#define N_NODES 100000
#define N_EDGES 3200000
#define R_REL   8
#define C_IN    128
#define HID     64
#define WCOLS   576   // 8 relations * 64 + 64 (root slot)

// counting-sort parameters
#define NBUCK 500     // dst buckets
#define NPB   200     // nodes per bucket (500*200 = N)
#define NBLK  256     // edge chunks (long runs: CHUNK/NBUCK = 25 edges = 100 B)
#define CHUNK 12500   // E / NBLK (exact)
#define NCELL (NBUCK * NBLK)   // 128000
#define BCAP  7680    // LDS staging capacity per bucket (mean 6400, sigma ~80)

typedef __attribute__((ext_vector_type(8))) short  short8;
typedef __attribute__((ext_vector_type(4))) float  float4v;

__device__ __forceinline__ float bf2f(unsigned short u) {
    union { unsigned int i; float f; } v; v.i = ((unsigned int)u) << 16; return v.f;
}
__device__ __forceinline__ unsigned short f2bf(float f) {
    union { float f; unsigned int i; } v; v.f = f;
    unsigned int r = v.i + 0x7FFFu + ((v.i >> 16) & 1u);   // RNE
    return (unsigned short)(r >> 16);
}
__device__ __forceinline__ float rl_f(float v, int j) {
    union { float f; int i; } a, b; a.f = v;
    b.i = __builtin_amdgcn_readlane(a.i, j);
    return b.f;
}

// ---------------- weight prep (f32 -> bf16, concatenated+transposed) ----------
__global__ void prep_wcat(const float* __restrict__ W1,
                          const float* __restrict__ root1,
                          const float* __restrict__ W2,
                          const float* __restrict__ root2,
                          unsigned short* __restrict__ BT1,
                          unsigned short* __restrict__ BT2) {
    int idx = blockIdx.x * 256 + threadIdx.x;
    const int T1 = WCOLS * C_IN;          // 73728
    const int T2 = WCOLS * HID;           // 36864
    if (idx < T1) {
        int c = idx / C_IN, k = idx % C_IN;
        float v;
        if (c < 512) { int r = c >> 6, h = c & 63; v = W1[r * (C_IN * 64) + k * 64 + h]; }
        else         { v = root1[k * 64 + (c - 512)]; }
        BT1[idx] = f2bf(v);
    } else if (idx < T1 + T2) {
        int j = idx - T1;
        int c = j / HID, k = j % HID;
        float v;
        if (c < 512) { int r = c >> 6, h = c & 63; v = W2[r * (HID * 64) + k * 64 + h]; }
        else         { v = root2[k * 64 + (c - 512)]; }
        BT2[j] = f2bf(v);
    }
}

// ---------------- K1: per-block LDS counting sort, sequential writes ---------
// esort[blk*CHUNK...] = block's edges sorted by bucket (packed src<<11|dl<<3|rel)
// bcountT[blk*NBUCK+b] = count; lstartT[blk*NBUCK+b] = local exclusive prefix.
__global__ __launch_bounds__(512)
void edge_sort_local(const int* __restrict__ src, const int* __restrict__ dst,
                     const int* __restrict__ et,
                     unsigned int* __restrict__ esort,
                     int* __restrict__ bcountT, int* __restrict__ lstartT) {
    __shared__ int cnt[NBUCK], cur[NBUCK], tsum[512];
    __shared__ unsigned int sedge[CHUNK];               // 50 KB
    const int blk = blockIdx.x, tid = threadIdx.x;
    const int e0 = blk * CHUNK;

    for (int i = tid; i < NBUCK; i += 512) cnt[i] = 0;
    __syncthreads();
    for (int i = tid; i < CHUNK; i += 512)
        atomicAdd(&cnt[dst[e0 + i] / NPB], 1);
    __syncthreads();

    int v = (tid < NBUCK) ? cnt[tid] : 0;
    tsum[tid] = v; __syncthreads();
    for (int off = 1; off < 512; off <<= 1) {
        int t = (tid >= off) ? tsum[tid - off] : 0;
        __syncthreads(); tsum[tid] += t; __syncthreads();
    }
    if (tid < NBUCK) cur[tid] = tsum[tid] - v;
    __syncthreads();

    for (int b = tid; b < NBUCK; b += 512) {
        bcountT[blk * NBUCK + b] = cnt[b];
        lstartT[blk * NBUCK + b] = cur[b];
    }
    __syncthreads();

    for (int i = tid; i < CHUNK; i += 512) {
        int d = dst[e0 + i];
        int b = d / NPB;
        int pos = atomicAdd(&cur[b], 1);
        sedge[pos] = ((unsigned int)src[e0 + i] << 11) |
                     ((unsigned int)(d - b * NPB) << 3) | (unsigned int)et[e0 + i];
    }
    __syncthreads();
    for (int i = tid; i < CHUNK; i += 512) esort[e0 + i] = sedge[i];
}

// ---------------- bucket totals + scan over 500 buckets ----------------------
__global__ __launch_bounds__(256)
void btot_sum(const int* __restrict__ bcountT, int* __restrict__ btot) {
    __shared__ int tsum[256];
    const int b = blockIdx.x, tid = threadIdx.x;
    int s = 0;
    for (int blk = tid; blk < NBLK; blk += 256) s += bcountT[blk * NBUCK + b];
    tsum[tid] = s; __syncthreads();
    for (int off = 128; off > 0; off >>= 1) {
        if (tid < off) tsum[tid] += tsum[tid + off];
        __syncthreads();
    }
    if (tid == 0) btot[b] = tsum[0];
}

__global__ __launch_bounds__(512)
void scan_btot(int* __restrict__ btot, int nb) {   // nb <= 512, exclusive in place
    __shared__ int tmp[512];
    int tid = threadIdx.x;
    int v = (tid < nb) ? btot[tid] : 0;
    tmp[tid] = v; __syncthreads();
    for (int off = 1; off < 512; off <<= 1) {
        int t = (tid >= off) ? tmp[tid - off] : 0;
        __syncthreads(); tmp[tid] += t; __syncthreads();
    }
    if (tid < nb) btot[tid] = tmp[tid] - v;
}

// ---------------- bucket_build: LDS-staged CSR emit, rowstart8 ---------------
// one block per bucket. Emits elist (precomputed XW offsets) and the full
// per-(node,rel) boundary table rowstart8[n*8+r] — weights are derived in
// agg_fused from segment lengths.
__global__ __launch_bounds__(512)
void bucket_build(const unsigned int* __restrict__ esort,
                  const int* __restrict__ bcountT, const int* __restrict__ lstartT,
                  const int* __restrict__ btot,
                  unsigned int* __restrict__ elist,
                  int* __restrict__ rowstart8) {
    __shared__ int   cnt[2048], cur[2048], tsum[512];   // 8192+8192+2048 B
    __shared__ int   rlen[NBLK], rpos[NBLK], rloff[NBLK]; // 3072 B
    __shared__ unsigned int sedge[BCAP];                // 30720 B
    __shared__ unsigned int selist[BCAP];               // 30720 B  (total ~83 KB)

    const int b = blockIdx.x, tid = threadIdx.x;
    const int seg0 = btot[b];

    for (int i = tid; i < 2048; i += 512) cnt[i] = 0;
    if (tid < NBLK) {
        rlen[tid] = bcountT[tid * NBUCK + b];
        rpos[tid] = tid * CHUNK + lstartT[tid * NBUCK + b];
    }
    __syncthreads();

    int rv = (tid < NBLK) ? rlen[tid] : 0;
    tsum[tid] = rv; __syncthreads();
    for (int off = 1; off < 512; off <<= 1) {
        int t = (tid >= off) ? tsum[tid - off] : 0;
        __syncthreads(); tsum[tid] += t; __syncthreads();
    }
    if (tid < NBLK) rloff[tid] = tsum[tid] - rv;
    const int total = tsum[NBLK - 1];       // bucket edge count
    __syncthreads();
    const bool fits = (total <= BCAP);      // safety fallback

    // ---- pass 1: flat stage + histogram (esort read once) ----
    for (int i = tid; i < total; i += 512) {
        int lo = 0, hi = NBLK - 1;          // largest blk with rloff[blk] <= i
        while (lo < hi) { int mid = (lo + hi + 1) >> 1; if (rloff[mid] <= i) lo = mid; else hi = mid - 1; }
        unsigned int e = esort[rpos[lo] + (i - rloff[lo])];
        if (fits) sedge[i] = e;
        atomicAdd(&cnt[(int)((e >> 3) & 255u) * 8 + (int)(e & 7u)], 1);
    }
    __syncthreads();

    // ---- exclusive scan over 2048 counters ----
    int base = tid * 4, s = 0, loc[4];
#pragma unroll
    for (int k = 0; k < 4; ++k) { loc[k] = s; s += cnt[base + k]; }
    tsum[tid] = s; __syncthreads();
    for (int off = 1; off < 512; off <<= 1) {
        int t = (tid >= off) ? tsum[tid - off] : 0;
        __syncthreads(); tsum[tid] += t; __syncthreads();
    }
    int texcl = tsum[tid] - s;
#pragma unroll
    for (int k = 0; k < 4; ++k) cur[base + k] = texcl + loc[k];
    __syncthreads();

    for (int i = tid; i < NPB * 8; i += 512)
        rowstart8[(b * NPB) * 8 + i] = seg0 + cur[i];
    if (b == NBUCK - 1 && tid == 0) rowstart8[N_NODES * 8] = N_EDGES;
    __syncthreads();

    // ---- pass 2: flat emit into LDS (scatter stays on-chip) ----
    for (int i = tid; i < total; i += 512) {
        unsigned int e;
        if (fits) e = sedge[i];
        else {
            int lo = 0, hi = NBLK - 1;
            while (lo < hi) { int mid = (lo + hi + 1) >> 1; if (rloff[mid] <= i) lo = mid; else hi = mid - 1; }
            e = esort[rpos[lo] + (i - rloff[lo])];
        }
        int r = (int)(e & 7u);
        int j = (int)((e >> 3) & 255u) * 8 + r;
        int p = atomicAdd(&cur[j], 1);
        unsigned int eo = (e >> 11) * WCOLS + (unsigned int)(r * 64);
        if (fits) selist[p] = eo;
        else      elist[seg0 + p] = eo;
    }
    __syncthreads();

    if (fits) {
        for (int i = tid; i < total; i += 512)
            elist[seg0 + i] = selist[i];
    }
}

// ---------------- GEMM: Out[N][576] (bf16) = A[N][K] @ Wcat ------------------
template <int K, bool AF32>
__global__ __launch_bounds__(256)
void gemm_rows(const void* __restrict__ Araw,
               const unsigned short* __restrict__ BT,
               unsigned short* __restrict__ Out, int nrows) {
    constexpr int KSTEPS = K / 32;
    constexpr int LDB = K + 8;
    __shared__ __align__(16) unsigned short Blds[64 * LDB];
    __shared__ __align__(16) unsigned short stage[4][16 * 64];

    const int wave = threadIdx.x >> 6;
    const int lane = threadIdx.x & 63;
    const int l15 = lane & 15, quad = lane >> 4;
    const int rowbase = blockIdx.x * 64 + wave * 16;
    int arow = rowbase + l15;
    if (arow >= nrows) arow = nrows - 1;

    short8 afrag[KSTEPS];
    if constexpr (AF32) {
        const float* Af = (const float*)Araw;
#pragma unroll
        for (int ks = 0; ks < KSTEPS; ++ks) {
            const float* p = Af + (size_t)arow * K + ks * 32 + quad * 8;
            float4v u0 = *(const float4v*)p;
            float4v u1 = *(const float4v*)(p + 4);
            short8 f;
            f[0] = (short)f2bf(u0[0]); f[1] = (short)f2bf(u0[1]);
            f[2] = (short)f2bf(u0[2]); f[3] = (short)f2bf(u0[3]);
            f[4] = (short)f2bf(u1[0]); f[5] = (short)f2bf(u1[1]);
            f[6] = (short)f2bf(u1[2]); f[7] = (short)f2bf(u1[3]);
            afrag[ks] = f;
        }
    } else {
        const unsigned short* Ab = (const unsigned short*)Araw;
#pragma unroll
        for (int ks = 0; ks < KSTEPS; ++ks)
            afrag[ks] = *(const short8*)(Ab + (size_t)arow * K + ks * 32 + quad * 8);
    }

    for (int chunk = 0; chunk < 9; ++chunk) {
        __syncthreads();
        {
            const unsigned short* src = BT + (size_t)chunk * 64 * K;
            const int nvec = 64 * K / 8;
            for (int i = threadIdx.x; i < nvec; i += 256) {
                int r = i / (K / 8);
                int cpos = (i % (K / 8)) * 8;
                *(uint4*)(&Blds[r * LDB + cpos]) = *(const uint4*)(src + r * K + cpos);
            }
        }
        __syncthreads();

        float4v acc[4];
#pragma unroll
        for (int ct = 0; ct < 4; ++ct) { acc[ct][0] = 0.f; acc[ct][1] = 0.f; acc[ct][2] = 0.f; acc[ct][3] = 0.f; }

#pragma unroll
        for (int ct = 0; ct < 4; ++ct) {
#pragma unroll
            for (int ks = 0; ks < KSTEPS; ++ks) {
                short8 bfrag = *(const short8*)(&Blds[(ct * 16 + l15) * LDB + ks * 32 + quad * 8]);
                acc[ct] = __builtin_amdgcn_mfma_f32_16x16x32_bf16(afrag[ks], bfrag, acc[ct], 0, 0, 0);
            }
        }

#pragma unroll
        for (int ct = 0; ct < 4; ++ct)
#pragma unroll
            for (int r = 0; r < 4; ++r)
                stage[wave][(quad * 4 + r) * 64 + ct * 16 + l15] = f2bf(acc[ct][r]);
        __syncthreads();

        {
            int r = lane >> 2, j = lane & 3;
            int orow = rowbase + r;
            if (orow < nrows) {
#pragma unroll
                for (int p = 0; p < 2; ++p) {
                    int c0 = (j + p * 4) * 8;
                    uint4 v = *(const uint4*)&stage[wave][r * 64 + c0];
                    *(uint4*)(Out + (size_t)orow * WCOLS + chunk * 64 + c0) = v;
                }
            }
        }
    }
}

// ---------------- fused CSR aggregate + root + bias (+relu) ------------------
// one wave per node, lane = channel. 16-deep explicit gather pipeline.
// Weights derived from per-(node,rel) segment boundaries (rowstart8).
template <int MODE>   // 0: relu -> bf16 h ; 1: -> f32 out
__global__ __launch_bounds__(256)
void agg_fused(const unsigned short* __restrict__ XW,
               const unsigned int* __restrict__ elist,
               const int* __restrict__ rowstart8,
               const float* __restrict__ bias,
               void* __restrict__ outp) {
    const int wave = threadIdx.x >> 6, lane = threadIdx.x & 63;
    const int n = blockIdx.x * 4 + wave;          // grid covers N exactly
    int r9 = 0;
    if (lane < 9) r9 = rowstart8[n * 8 + lane];
    const int b0 = __builtin_amdgcn_readlane(r9, 0);
    const int b1 = __builtin_amdgcn_readlane(r9, 1);
    const int b2 = __builtin_amdgcn_readlane(r9, 2);
    const int b3 = __builtin_amdgcn_readlane(r9, 3);
    const int b4 = __builtin_amdgcn_readlane(r9, 4);
    const int b5 = __builtin_amdgcn_readlane(r9, 5);
    const int b6 = __builtin_amdgcn_readlane(r9, 6);
    const int b7 = __builtin_amdgcn_readlane(r9, 7);
    const int b8 = __builtin_amdgcn_readlane(r9, 8);
    const int beg = b0, end = b8;

    auto invlen = [](int a, int bnd) {
        int l = bnd - a; return 1.0f / (float)(l > 1 ? l : 1);
    };
    const float il0 = invlen(b0, b1), il1 = invlen(b1, b2);
    const float il2 = invlen(b2, b3), il3 = invlen(b3, b4);
    const float il4 = invlen(b4, b5), il5 = invlen(b5, b6);
    const float il6 = invlen(b6, b7), il7 = invlen(b7, b8);

    const unsigned short* XWl = XW + lane;        // fold lane offset into base

    float acc = 0.f;
    int i = beg;
    while (i < end) {
        int m = end - i; if (m > 64) m = 64;
        int idx = i + lane; if (idx >= end) idx = end - 1;
        unsigned int ub = elist[idx];             // offset (coalesced, 1 load / 64 edges)
        // per-lane weight from segment membership (cmp+sel chain, ~15 VALU/chunk)
        float wb = il0;
        wb = (idx >= b1) ? il1 : wb;
        wb = (idx >= b2) ? il2 : wb;
        wb = (idx >= b3) ? il3 : wb;
        wb = (idx >= b4) ? il4 : wb;
        wb = (idx >= b5) ? il5 : wb;
        wb = (idx >= b6) ? il6 : wb;
        wb = (idx >= b7) ? il7 : wb;

        int j = 0;
        for (; j + 16 <= m; j += 16) {
            float vv[16], ww[16];
#pragma unroll
            for (int t = 0; t < 16; ++t) {
                unsigned int u = (unsigned int)__builtin_amdgcn_readlane((int)ub, j + t);
                ww[t] = rl_f(wb, j + t);
                vv[t] = bf2f(XWl[u]);
            }
#pragma unroll
            for (int t = 0; t < 16; ++t) acc += ww[t] * vv[t];
        }
        for (; j + 4 <= m; j += 4) {
            float vv[4], ww[4];
#pragma unroll
            for (int t = 0; t < 4; ++t) {
                unsigned int u = (unsigned int)__builtin_amdgcn_readlane((int)ub, j + t);
                ww[t] = rl_f(wb, j + t);
                vv[t] = bf2f(XWl[u]);
            }
#pragma unroll
            for (int t = 0; t < 4; ++t) acc += ww[t] * vv[t];
        }
        for (; j < m; ++j) {
            unsigned int u = (unsigned int)__builtin_amdgcn_readlane((int)ub, j);
            float w = rl_f(wb, j);
            acc += w * bf2f(XWl[u]);
        }
        i += m;
    }

    float res = acc + bf2f(XW[(size_t)n * WCOLS + 512 + lane]) + bias[lane];
    if (MODE == 0) {
        res = res > 0.f ? res : 0.f;
        ((unsigned short*)outp)[(size_t)n * 64 + lane] = f2bf(res);
    } else {
        ((float*)outp)[(size_t)n * 64 + lane] = res;
    }
}

// ---------------- launch ------------------------------------------------------
extern "C" void kernel_launch(void* const* d_in, const int* in_sizes, int n_in,
                              void* d_out, int out_size, void* d_ws, size_t ws_size,
                              hipStream_t stream) {
    const float* x     = (const float*)d_in[0];
    const int*   eidx  = (const int*)d_in[1];
    const int*   etyp  = (const int*)d_in[2];
    const float* W1    = (const float*)d_in[3];
    const float* root1 = (const float*)d_in[4];
    const float* b1    = (const float*)d_in[5];
    const float* W2    = (const float*)d_in[6];
    const float* root2 = (const float*)d_in[7];
    const float* b2    = (const float*)d_in[8];
    float*       out   = (float*)d_out;

    char* ws = (char*)d_ws;
    size_t off = 0;
    auto alloc = [&](size_t bytes) { char* p = ws + off; off += (bytes + 255) & ~(size_t)255; return p; };

    unsigned short* xW       = (unsigned short*)alloc((size_t)N_NODES * WCOLS * 2); // 115.2 MB (reused as hW)
    unsigned short* h        = (unsigned short*)alloc((size_t)N_NODES * HID * 2);   //  12.8 MB
    unsigned int*   elist    = (unsigned int*)alloc((size_t)N_EDGES * 4);           //  12.8 MB
    int*            rowstart8= (int*)alloc(((size_t)N_NODES * 8 + 1) * 4);          //   3.2 MB
    unsigned short* BT1      = (unsigned short*)alloc((size_t)WCOLS * C_IN * 2);
    unsigned short* BT2      = (unsigned short*)alloc((size_t)WCOLS * HID * 2);
    // total ~144.5 MB

    // sort scratch aliases into xW (dead before gemm1 writes xW)
    unsigned int* esort   = (unsigned int*)xW;                          // 12.8 MB
    int*          bcountT = (int*)((char*)xW + (size_t)N_EDGES * 4);    //  0.5 MB
    int*          lstartT = bcountT + NCELL;                            //  0.5 MB
    int*          btot    = lstartT + NCELL;                            //  2 KB

    const int* srcp = eidx;
    const int* dstp = eidx + N_EDGES;

    prep_wcat<<<(WCOLS * (C_IN + HID) + 255) / 256, 256, 0, stream>>>(W1, root1, W2, root2, BT1, BT2);

    // CSR build — sequential-write sort + fused per-bucket CSR emit
    edge_sort_local<<<NBLK, 512, 0, stream>>>(srcp, dstp, etyp, esort, bcountT, lstartT);
    btot_sum<<<NBUCK, 256, 0, stream>>>(bcountT, btot);
    scan_btot<<<1, 512, 0, stream>>>(btot, NBUCK);
    bucket_build<<<NBUCK, 512, 0, stream>>>(esort, bcountT, lstartT, btot, elist, rowstart8);

    const int gemm_grid = (N_NODES + 63) / 64;    // 1563
    const int agg_grid  = N_NODES / 4;            // 25000

    // layer 1: x (f32) -> xW (bf16) -> h (bf16, relu)
    gemm_rows<C_IN, true><<<gemm_grid, 256, 0, stream>>>((const void*)x, BT1, xW, N_NODES);
    agg_fused<0><<<agg_grid, 256, 0, stream>>>(xW, elist, rowstart8, b1, (void*)h);

    // layer 2: h -> hW (reuse xW) -> out (f32)
    gemm_rows<HID, false><<<gemm_grid, 256, 0, stream>>>((const void*)h, BT2, xW, N_NODES);
    agg_fused<1><<<agg_grid, 256, 0, stream>>>(xW, elist, rowstart8, b2, (void*)out);
}

// Round 6
// 380.625 us; speedup vs baseline: 1.3193x; 1.0797x over previous
//
#include <hip/hip_runtime.h>

#define N_NODES 100000
#define N_EDGES 3200000
#define R_REL   8
#define C_IN    128
#define HID     64
#define WCOLS   576   // 8 relations * 64 + 64 (root slot)

// counting-sort parameters
#define NBUCK 500     // dst buckets
#define NPB   200     // nodes per bucket (500*200 = N)
#define NBLK  256     // edge chunks (long runs: CHUNK/NBUCK = 25 edges = 100 B)
#define CHUNK 12500   // E / NBLK (exact)
#define NCELL (NBUCK * NBLK)   // 128000
#define BCAP  7680    // LDS staging capacity per bucket (mean 6400, sigma ~80)

typedef __attribute__((ext_vector_type(8))) short  short8;
typedef __attribute__((ext_vector_type(4))) float  float4v;

__device__ __forceinline__ float bf2f(unsigned short u) {
    union { unsigned int i; float f; } v; v.i = ((unsigned int)u) << 16; return v.f;
}
__device__ __forceinline__ unsigned short f2bf(float f) {
    union { float f; unsigned int i; } v; v.f = f;
    unsigned int r = v.i + 0x7FFFu + ((v.i >> 16) & 1u);   // RNE
    return (unsigned short)(r >> 16);
}
__device__ __forceinline__ float rl_f(float v, int j) {
    union { float f; int i; } a, b; a.f = v;
    b.i = __builtin_amdgcn_readlane(a.i, j);
    return b.f;
}

// ---------------- weight prep (f32 -> bf16, concatenated+transposed) ----------
__global__ void prep_wcat(const float* __restrict__ W1,
                          const float* __restrict__ root1,
                          const float* __restrict__ W2,
                          const float* __restrict__ root2,
                          unsigned short* __restrict__ BT1,
                          unsigned short* __restrict__ BT2) {
    int idx = blockIdx.x * 256 + threadIdx.x;
    const int T1 = WCOLS * C_IN;          // 73728
    const int T2 = WCOLS * HID;           // 36864
    if (idx < T1) {
        int c = idx / C_IN, k = idx % C_IN;
        float v;
        if (c < 512) { int r = c >> 6, h = c & 63; v = W1[r * (C_IN * 64) + k * 64 + h]; }
        else         { v = root1[k * 64 + (c - 512)]; }
        BT1[idx] = f2bf(v);
    } else if (idx < T1 + T2) {
        int j = idx - T1;
        int c = j / HID, k = j % HID;
        float v;
        if (c < 512) { int r = c >> 6, h = c & 63; v = W2[r * (HID * 64) + k * 64 + h]; }
        else         { v = root2[k * 64 + (c - 512)]; }
        BT2[j] = f2bf(v);
    }
}

// ---------------- K1: per-block LDS counting sort, sequential writes ---------
// esort[blk*CHUNK...] = block's edges sorted by bucket (packed src<<11|dl<<3|rel)
// bcountT[blk*NBUCK+b] = count; lstartT[blk*NBUCK+b] = local exclusive prefix.
// 1024 threads (16 waves/CU at 1 block/CU) to hide LDS-atomic + scan latency.
__global__ __launch_bounds__(1024)
void edge_sort_local(const int* __restrict__ src, const int* __restrict__ dst,
                     const int* __restrict__ et,
                     unsigned int* __restrict__ esort,
                     int* __restrict__ bcountT, int* __restrict__ lstartT) {
    __shared__ int cnt[NBUCK], cur[NBUCK], tsum[1024];
    __shared__ unsigned int sedge[CHUNK];               // 50 KB
    const int blk = blockIdx.x, tid = threadIdx.x;
    const int e0 = blk * CHUNK;

    for (int i = tid; i < NBUCK; i += 1024) cnt[i] = 0;
    __syncthreads();
    for (int i = tid; i < CHUNK; i += 1024)
        atomicAdd(&cnt[dst[e0 + i] / NPB], 1);
    __syncthreads();

    // exclusive scan over 500 counters (Hillis-Steele over 1024)
    int v = (tid < NBUCK) ? cnt[tid] : 0;
    tsum[tid] = v; __syncthreads();
    for (int off = 1; off < 1024; off <<= 1) {
        int t = (tid >= off) ? tsum[tid - off] : 0;
        __syncthreads(); tsum[tid] += t; __syncthreads();
    }
    if (tid < NBUCK) cur[tid] = tsum[tid] - v;
    __syncthreads();

    for (int b = tid; b < NBUCK; b += 1024) {
        bcountT[blk * NBUCK + b] = cnt[b];
        lstartT[blk * NBUCK + b] = cur[b];
    }
    __syncthreads();

    for (int i = tid; i < CHUNK; i += 1024) {
        int d = dst[e0 + i];
        int b = d / NPB;
        int pos = atomicAdd(&cur[b], 1);
        sedge[pos] = ((unsigned int)src[e0 + i] << 11) |
                     ((unsigned int)(d - b * NPB) << 3) | (unsigned int)et[e0 + i];
    }
    __syncthreads();
    for (int i = tid; i < CHUNK; i += 1024) esort[e0 + i] = sedge[i];
}

// ---------------- bucket_build: LDS-staged CSR emit, rowstart8 ---------------
// one block per bucket, 1024 threads. Computes its own global segment base
// seg0 = sum_blk lstartT[blk][b]  (sum of per-block exclusive prefixes ==
// global exclusive prefix of bucket b) — btot_sum/scan_btot kernels removed.
__global__ __launch_bounds__(1024)
void bucket_build(const unsigned int* __restrict__ esort,
                  const int* __restrict__ bcountT, const int* __restrict__ lstartT,
                  unsigned int* __restrict__ elist,
                  int* __restrict__ rowstart8) {
    __shared__ int   cnt[2048], cur[2048], tsum[1024];  // 8192+8192+4096 B
    __shared__ int   rpos[NBLK], rloff[NBLK];           // 2048 B
    __shared__ unsigned int sedge[BCAP];                // 30720 B
    __shared__ unsigned int selist[BCAP];               // 30720 B  (total ~84 KB)

    const int b = blockIdx.x, tid = threadIdx.x;

    for (int i = tid; i < 2048; i += 1024) cnt[i] = 0;
    int myrl = 0, myls = 0;
    if (tid < NBLK) {
        myrl = bcountT[tid * NBUCK + b];
        myls = lstartT[tid * NBUCK + b];
        rpos[tid] = tid * CHUNK + myls;
    }
    __syncthreads();

    // ---- scan run lengths (Hillis-Steele over 1024; entries >=NBLK are 0) ----
    tsum[tid] = myrl; __syncthreads();
    for (int off = 1; off < 1024; off <<= 1) {
        int t = (tid >= off) ? tsum[tid - off] : 0;
        __syncthreads(); tsum[tid] += t; __syncthreads();
    }
    const int total = tsum[NBLK - 1];       // bucket edge count
    if (tid < NBLK) rloff[tid] = tsum[tid] - myrl;
    __syncthreads();

    // ---- seg0 = sum of per-block local prefixes (tree reduce) ----
    tsum[tid] = myls; __syncthreads();
    for (int off = 512; off > 0; off >>= 1) {
        if (tid < off) tsum[tid] += tsum[tid + off];
        __syncthreads();
    }
    const int seg0 = tsum[0];
    __syncthreads();
    const bool fits = (total <= BCAP);      // safety fallback

    // ---- pass 1: flat stage + histogram (esort read once) ----
    for (int i = tid; i < total; i += 1024) {
        int lo = 0, hi = NBLK - 1;          // largest blk with rloff[blk] <= i
        while (lo < hi) { int mid = (lo + hi + 1) >> 1; if (rloff[mid] <= i) lo = mid; else hi = mid - 1; }
        unsigned int e = esort[rpos[lo] + (i - rloff[lo])];
        if (fits) sedge[i] = e;
        atomicAdd(&cnt[(int)((e >> 3) & 255u) * 8 + (int)(e & 7u)], 1);
    }
    __syncthreads();

    // ---- exclusive scan over 2048 counters: 2/thread + Hillis-Steele ----
    int base = tid * 2;
    int c0 = cnt[base], c1 = cnt[base + 1];
    int s = c0 + c1;
    tsum[tid] = s; __syncthreads();
    for (int off = 1; off < 1024; off <<= 1) {
        int t = (tid >= off) ? tsum[tid - off] : 0;
        __syncthreads(); tsum[tid] += t; __syncthreads();
    }
    int texcl = tsum[tid] - s;
    cur[base] = texcl; cur[base + 1] = texcl + c0;
    __syncthreads();

    // ---- per-(node,rel) boundary table ----
    for (int i = tid; i < NPB * 8; i += 1024)
        rowstart8[(b * NPB) * 8 + i] = seg0 + cur[i];
    if (b == NBUCK - 1 && tid == 0) rowstart8[N_NODES * 8] = N_EDGES;
    __syncthreads();

    // ---- pass 2: flat emit into LDS (scatter stays on-chip) ----
    for (int i = tid; i < total; i += 1024) {
        unsigned int e;
        if (fits) e = sedge[i];
        else {
            int lo = 0, hi = NBLK - 1;
            while (lo < hi) { int mid = (lo + hi + 1) >> 1; if (rloff[mid] <= i) lo = mid; else hi = mid - 1; }
            e = esort[rpos[lo] + (i - rloff[lo])];
        }
        int r = (int)(e & 7u);
        int j = (int)((e >> 3) & 255u) * 8 + r;
        int p = atomicAdd(&cur[j], 1);
        unsigned int eo = (e >> 11) * WCOLS + (unsigned int)(r * 64);
        if (fits) selist[p] = eo;
        else      elist[seg0 + p] = eo;
    }
    __syncthreads();

    if (fits) {
        for (int i = tid; i < total; i += 1024)
            elist[seg0 + i] = selist[i];
    }
}

// ---------------- GEMM: Out[N][576] (bf16) = A[N][K] @ Wcat ------------------
template <int K, bool AF32>
__global__ __launch_bounds__(256)
void gemm_rows(const void* __restrict__ Araw,
               const unsigned short* __restrict__ BT,
               unsigned short* __restrict__ Out, int nrows) {
    constexpr int KSTEPS = K / 32;
    constexpr int LDB = K + 8;
    __shared__ __align__(16) unsigned short Blds[64 * LDB];
    __shared__ __align__(16) unsigned short stage[4][16 * 64];

    const int wave = threadIdx.x >> 6;
    const int lane = threadIdx.x & 63;
    const int l15 = lane & 15, quad = lane >> 4;
    const int rowbase = blockIdx.x * 64 + wave * 16;
    int arow = rowbase + l15;
    if (arow >= nrows) arow = nrows - 1;

    short8 afrag[KSTEPS];
    if constexpr (AF32) {
        const float* Af = (const float*)Araw;
#pragma unroll
        for (int ks = 0; ks < KSTEPS; ++ks) {
            const float* p = Af + (size_t)arow * K + ks * 32 + quad * 8;
            float4v u0 = *(const float4v*)p;
            float4v u1 = *(const float4v*)(p + 4);
            short8 f;
            f[0] = (short)f2bf(u0[0]); f[1] = (short)f2bf(u0[1]);
            f[2] = (short)f2bf(u0[2]); f[3] = (short)f2bf(u0[3]);
            f[4] = (short)f2bf(u1[0]); f[5] = (short)f2bf(u1[1]);
            f[6] = (short)f2bf(u1[2]); f[7] = (short)f2bf(u1[3]);
            afrag[ks] = f;
        }
    } else {
        const unsigned short* Ab = (const unsigned short*)Araw;
#pragma unroll
        for (int ks = 0; ks < KSTEPS; ++ks)
            afrag[ks] = *(const short8*)(Ab + (size_t)arow * K + ks * 32 + quad * 8);
    }

    for (int chunk = 0; chunk < 9; ++chunk) {
        __syncthreads();
        {
            const unsigned short* src = BT + (size_t)chunk * 64 * K;
            const int nvec = 64 * K / 8;
            for (int i = threadIdx.x; i < nvec; i += 256) {
                int r = i / (K / 8);
                int cpos = (i % (K / 8)) * 8;
                *(uint4*)(&Blds[r * LDB + cpos]) = *(const uint4*)(src + r * K + cpos);
            }
        }
        __syncthreads();

        float4v acc[4];
#pragma unroll
        for (int ct = 0; ct < 4; ++ct) { acc[ct][0] = 0.f; acc[ct][1] = 0.f; acc[ct][2] = 0.f; acc[ct][3] = 0.f; }

#pragma unroll
        for (int ct = 0; ct < 4; ++ct) {
#pragma unroll
            for (int ks = 0; ks < KSTEPS; ++ks) {
                short8 bfrag = *(const short8*)(&Blds[(ct * 16 + l15) * LDB + ks * 32 + quad * 8]);
                acc[ct] = __builtin_amdgcn_mfma_f32_16x16x32_bf16(afrag[ks], bfrag, acc[ct], 0, 0, 0);
            }
        }

#pragma unroll
        for (int ct = 0; ct < 4; ++ct)
#pragma unroll
            for (int r = 0; r < 4; ++r)
                stage[wave][(quad * 4 + r) * 64 + ct * 16 + l15] = f2bf(acc[ct][r]);
        __syncthreads();

        {
            int r = lane >> 2, j = lane & 3;
            int orow = rowbase + r;
            if (orow < nrows) {
#pragma unroll
                for (int p = 0; p < 2; ++p) {
                    int c0 = (j + p * 4) * 8;
                    uint4 v = *(const uint4*)&stage[wave][r * 64 + c0];
                    *(uint4*)(Out + (size_t)orow * WCOLS + chunk * 64 + c0) = v;
                }
            }
        }
    }
}

// ---------------- fused CSR aggregate + root + bias (+relu) ------------------
// one wave per node, lane = channel. 16-deep explicit gather pipeline.
// Weights derived from per-(node,rel) segment boundaries (rowstart8).
template <int MODE>   // 0: relu -> bf16 h ; 1: -> f32 out
__global__ __launch_bounds__(256)
void agg_fused(const unsigned short* __restrict__ XW,
               const unsigned int* __restrict__ elist,
               const int* __restrict__ rowstart8,
               const float* __restrict__ bias,
               void* __restrict__ outp) {
    const int wave = threadIdx.x >> 6, lane = threadIdx.x & 63;
    const int n = blockIdx.x * 4 + wave;          // grid covers N exactly
    int r9 = 0;
    if (lane < 9) r9 = rowstart8[n * 8 + lane];
    const int b0 = __builtin_amdgcn_readlane(r9, 0);
    const int b1 = __builtin_amdgcn_readlane(r9, 1);
    const int b2 = __builtin_amdgcn_readlane(r9, 2);
    const int b3 = __builtin_amdgcn_readlane(r9, 3);
    const int b4 = __builtin_amdgcn_readlane(r9, 4);
    const int b5 = __builtin_amdgcn_readlane(r9, 5);
    const int b6 = __builtin_amdgcn_readlane(r9, 6);
    const int b7 = __builtin_amdgcn_readlane(r9, 7);
    const int b8 = __builtin_amdgcn_readlane(r9, 8);
    const int beg = b0, end = b8;

    auto invlen = [](int a, int bnd) {
        int l = bnd - a; return 1.0f / (float)(l > 1 ? l : 1);
    };
    const float il0 = invlen(b0, b1), il1 = invlen(b1, b2);
    const float il2 = invlen(b2, b3), il3 = invlen(b3, b4);
    const float il4 = invlen(b4, b5), il5 = invlen(b5, b6);
    const float il6 = invlen(b6, b7), il7 = invlen(b7, b8);

    const unsigned short* XWl = XW + lane;        // fold lane offset into base

    float acc = 0.f;
    int i = beg;
    while (i < end) {
        int m = end - i; if (m > 64) m = 64;
        int idx = i + lane; if (idx >= end) idx = end - 1;
        unsigned int ub = elist[idx];             // offset (coalesced, 1 load / 64 edges)
        // per-lane weight from segment membership (cmp+sel chain, ~15 VALU/chunk)
        float wb = il0;
        wb = (idx >= b1) ? il1 : wb;
        wb = (idx >= b2) ? il2 : wb;
        wb = (idx >= b3) ? il3 : wb;
        wb = (idx >= b4) ? il4 : wb;
        wb = (idx >= b5) ? il5 : wb;
        wb = (idx >= b6) ? il6 : wb;
        wb = (idx >= b7) ? il7 : wb;

        int j = 0;
        for (; j + 16 <= m; j += 16) {
            float vv[16], ww[16];
#pragma unroll
            for (int t = 0; t < 16; ++t) {
                unsigned int u = (unsigned int)__builtin_amdgcn_readlane((int)ub, j + t);
                ww[t] = rl_f(wb, j + t);
                vv[t] = bf2f(XWl[u]);
            }
#pragma unroll
            for (int t = 0; t < 16; ++t) acc += ww[t] * vv[t];
        }
        for (; j + 4 <= m; j += 4) {
            float vv[4], ww[4];
#pragma unroll
            for (int t = 0; t < 4; ++t) {
                unsigned int u = (unsigned int)__builtin_amdgcn_readlane((int)ub, j + t);
                ww[t] = rl_f(wb, j + t);
                vv[t] = bf2f(XWl[u]);
            }
#pragma unroll
            for (int t = 0; t < 4; ++t) acc += ww[t] * vv[t];
        }
        for (; j < m; ++j) {
            unsigned int u = (unsigned int)__builtin_amdgcn_readlane((int)ub, j);
            float w = rl_f(wb, j);
            acc += w * bf2f(XWl[u]);
        }
        i += m;
    }

    float res = acc + bf2f(XW[(size_t)n * WCOLS + 512 + lane]) + bias[lane];
    if (MODE == 0) {
        res = res > 0.f ? res : 0.f;
        ((unsigned short*)outp)[(size_t)n * 64 + lane] = f2bf(res);
    } else {
        ((float*)outp)[(size_t)n * 64 + lane] = res;
    }
}

// ---------------- launch ------------------------------------------------------
extern "C" void kernel_launch(void* const* d_in, const int* in_sizes, int n_in,
                              void* d_out, int out_size, void* d_ws, size_t ws_size,
                              hipStream_t stream) {
    const float* x     = (const float*)d_in[0];
    const int*   eidx  = (const int*)d_in[1];
    const int*   etyp  = (const int*)d_in[2];
    const float* W1    = (const float*)d_in[3];
    const float* root1 = (const float*)d_in[4];
    const float* b1    = (const float*)d_in[5];
    const float* W2    = (const float*)d_in[6];
    const float* root2 = (const float*)d_in[7];
    const float* b2    = (const float*)d_in[8];
    float*       out   = (float*)d_out;

    char* ws = (char*)d_ws;
    size_t off = 0;
    auto alloc = [&](size_t bytes) { char* p = ws + off; off += (bytes + 255) & ~(size_t)255; return p; };

    unsigned short* xW       = (unsigned short*)alloc((size_t)N_NODES * WCOLS * 2); // 115.2 MB (reused as hW)
    unsigned short* h        = (unsigned short*)alloc((size_t)N_NODES * HID * 2);   //  12.8 MB
    unsigned int*   elist    = (unsigned int*)alloc((size_t)N_EDGES * 4);           //  12.8 MB
    int*            rowstart8= (int*)alloc(((size_t)N_NODES * 8 + 1) * 4);          //   3.2 MB
    unsigned short* BT1      = (unsigned short*)alloc((size_t)WCOLS * C_IN * 2);
    unsigned short* BT2      = (unsigned short*)alloc((size_t)WCOLS * HID * 2);
    // total ~144.5 MB

    // sort scratch aliases into xW (dead before gemm1 writes xW)
    unsigned int* esort   = (unsigned int*)xW;                          // 12.8 MB
    int*          bcountT = (int*)((char*)xW + (size_t)N_EDGES * 4);    //  0.5 MB
    int*          lstartT = bcountT + NCELL;                            //  0.5 MB

    const int* srcp = eidx;
    const int* dstp = eidx + N_EDGES;

    prep_wcat<<<(WCOLS * (C_IN + HID) + 255) / 256, 256, 0, stream>>>(W1, root1, W2, root2, BT1, BT2);

    // CSR build — sequential-write sort + fused per-bucket CSR emit
    edge_sort_local<<<NBLK, 1024, 0, stream>>>(srcp, dstp, etyp, esort, bcountT, lstartT);
    bucket_build<<<NBUCK, 1024, 0, stream>>>(esort, bcountT, lstartT, elist, rowstart8);

    const int gemm_grid = (N_NODES + 63) / 64;    // 1563
    const int agg_grid  = N_NODES / 4;            // 25000

    // layer 1: x (f32) -> xW (bf16) -> h (bf16, relu)
    gemm_rows<C_IN, true><<<gemm_grid, 256, 0, stream>>>((const void*)x, BT1, xW, N_NODES);
    agg_fused<0><<<agg_grid, 256, 0, stream>>>(xW, elist, rowstart8, b1, (void*)h);

    // layer 2: h -> hW (reuse xW) -> out (f32)
    gemm_rows<HID, false><<<gemm_grid, 256, 0, stream>>>((const void*)h, BT2, xW, N_NODES);
    agg_fused<1><<<agg_grid, 256, 0, stream>>>(xW, elist, rowstart8, b2, (void*)out);
}

// Round 7
// 378.992 us; speedup vs baseline: 1.3250x; 1.0043x over previous
//
#include <hip/hip_runtime.h>

#define N_NODES 100000
#define N_EDGES 3200000
#define R_REL   8
#define C_IN    128
#define HID     64
#define WCOLS   576   // 8 relations * 64 + 64 (root slot)

// counting-sort parameters
#define NBUCK 500     // dst buckets
#define NPB   200     // nodes per bucket (500*200 = N)
#define NBLK  256     // edge chunks (long runs: CHUNK/NBUCK = 25 edges = 100 B)
#define CHUNK 12500   // E / NBLK (exact)
#define NCELL (NBUCK * NBLK)   // 128000
#define BCAP  7680    // LDS staging capacity per bucket (mean 6400, sigma ~80)

typedef __attribute__((ext_vector_type(8))) short  short8;
typedef __attribute__((ext_vector_type(4))) float  float4v;

__device__ __forceinline__ float bf2f(unsigned short u) {
    union { unsigned int i; float f; } v; v.i = ((unsigned int)u) << 16; return v.f;
}
__device__ __forceinline__ unsigned short f2bf(float f) {
    union { float f; unsigned int i; } v; v.f = f;
    unsigned int r = v.i + 0x7FFFu + ((v.i >> 16) & 1u);   // RNE
    return (unsigned short)(r >> 16);
}
__device__ __forceinline__ float rl_f(float v, int j) {
    union { float f; int i; } a, b; a.f = v;
    b.i = __builtin_amdgcn_readlane(a.i, j);
    return b.f;
}

// ---------------- weight prep (f32 -> bf16, concatenated+transposed) ----------
__global__ void prep_wcat(const float* __restrict__ W1,
                          const float* __restrict__ root1,
                          const float* __restrict__ W2,
                          const float* __restrict__ root2,
                          unsigned short* __restrict__ BT1,
                          unsigned short* __restrict__ BT2) {
    int idx = blockIdx.x * 256 + threadIdx.x;
    const int T1 = WCOLS * C_IN;          // 73728
    const int T2 = WCOLS * HID;           // 36864
    if (idx < T1) {
        int c = idx / C_IN, k = idx % C_IN;
        float v;
        if (c < 512) { int r = c >> 6, h = c & 63; v = W1[r * (C_IN * 64) + k * 64 + h]; }
        else         { v = root1[k * 64 + (c - 512)]; }
        BT1[idx] = f2bf(v);
    } else if (idx < T1 + T2) {
        int j = idx - T1;
        int c = j / HID, k = j % HID;
        float v;
        if (c < 512) { int r = c >> 6, h = c & 63; v = W2[r * (HID * 64) + k * 64 + h]; }
        else         { v = root2[k * 64 + (c - 512)]; }
        BT2[j] = f2bf(v);
    }
}

// ---------------- K1: per-block LDS counting sort, sequential writes ---------
__global__ __launch_bounds__(1024)
void edge_sort_local(const int* __restrict__ src, const int* __restrict__ dst,
                     const int* __restrict__ et,
                     unsigned int* __restrict__ esort,
                     int* __restrict__ bcountT, int* __restrict__ lstartT) {
    __shared__ int cnt[NBUCK], cur[NBUCK], tsum[1024];
    __shared__ unsigned int sedge[CHUNK];               // 50 KB
    const int blk = blockIdx.x, tid = threadIdx.x;
    const int e0 = blk * CHUNK;

    for (int i = tid; i < NBUCK; i += 1024) cnt[i] = 0;
    __syncthreads();
    for (int i = tid; i < CHUNK; i += 1024)
        atomicAdd(&cnt[dst[e0 + i] / NPB], 1);
    __syncthreads();

    int v = (tid < NBUCK) ? cnt[tid] : 0;
    tsum[tid] = v; __syncthreads();
    for (int off = 1; off < 1024; off <<= 1) {
        int t = (tid >= off) ? tsum[tid - off] : 0;
        __syncthreads(); tsum[tid] += t; __syncthreads();
    }
    if (tid < NBUCK) cur[tid] = tsum[tid] - v;
    __syncthreads();

    for (int b = tid; b < NBUCK; b += 1024) {
        bcountT[blk * NBUCK + b] = cnt[b];
        lstartT[blk * NBUCK + b] = cur[b];
    }
    __syncthreads();

    for (int i = tid; i < CHUNK; i += 1024) {
        int d = dst[e0 + i];
        int b = d / NPB;
        int pos = atomicAdd(&cur[b], 1);
        sedge[pos] = ((unsigned int)src[e0 + i] << 11) |
                     ((unsigned int)(d - b * NPB) << 3) | (unsigned int)et[e0 + i];
    }
    __syncthreads();
    for (int i = tid; i < CHUNK; i += 1024) esort[e0 + i] = sedge[i];
}

// ---------------- bucket_build: LDS-staged CSR emit, rowstart8 ---------------
__global__ __launch_bounds__(1024)
void bucket_build(const unsigned int* __restrict__ esort,
                  const int* __restrict__ bcountT, const int* __restrict__ lstartT,
                  unsigned int* __restrict__ elist,
                  int* __restrict__ rowstart8) {
    __shared__ int   cnt[2048], cur[2048], tsum[1024];  // 8192+8192+4096 B
    __shared__ int   rpos[NBLK], rloff[NBLK];           // 2048 B
    __shared__ unsigned int sedge[BCAP];                // 30720 B
    __shared__ unsigned int selist[BCAP];               // 30720 B  (total ~84 KB)

    const int b = blockIdx.x, tid = threadIdx.x;

    for (int i = tid; i < 2048; i += 1024) cnt[i] = 0;
    int myrl = 0, myls = 0;
    if (tid < NBLK) {
        myrl = bcountT[tid * NBUCK + b];
        myls = lstartT[tid * NBUCK + b];
        rpos[tid] = tid * CHUNK + myls;
    }
    __syncthreads();

    tsum[tid] = myrl; __syncthreads();
    for (int off = 1; off < 1024; off <<= 1) {
        int t = (tid >= off) ? tsum[tid - off] : 0;
        __syncthreads(); tsum[tid] += t; __syncthreads();
    }
    const int total = tsum[NBLK - 1];       // bucket edge count
    if (tid < NBLK) rloff[tid] = tsum[tid] - myrl;
    __syncthreads();

    tsum[tid] = myls; __syncthreads();
    for (int off = 512; off > 0; off >>= 1) {
        if (tid < off) tsum[tid] += tsum[tid + off];
        __syncthreads();
    }
    const int seg0 = tsum[0];
    __syncthreads();
    const bool fits = (total <= BCAP);      // safety fallback

    for (int i = tid; i < total; i += 1024) {
        int lo = 0, hi = NBLK - 1;          // largest blk with rloff[blk] <= i
        while (lo < hi) { int mid = (lo + hi + 1) >> 1; if (rloff[mid] <= i) lo = mid; else hi = mid - 1; }
        unsigned int e = esort[rpos[lo] + (i - rloff[lo])];
        if (fits) sedge[i] = e;
        atomicAdd(&cnt[(int)((e >> 3) & 255u) * 8 + (int)(e & 7u)], 1);
    }
    __syncthreads();

    int base = tid * 2;
    int c0 = cnt[base], c1 = cnt[base + 1];
    int s = c0 + c1;
    tsum[tid] = s; __syncthreads();
    for (int off = 1; off < 1024; off <<= 1) {
        int t = (tid >= off) ? tsum[tid - off] : 0;
        __syncthreads(); tsum[tid] += t; __syncthreads();
    }
    int texcl = tsum[tid] - s;
    cur[base] = texcl; cur[base + 1] = texcl + c0;
    __syncthreads();

    for (int i = tid; i < NPB * 8; i += 1024)
        rowstart8[(b * NPB) * 8 + i] = seg0 + cur[i];
    if (b == NBUCK - 1 && tid == 0) rowstart8[N_NODES * 8] = N_EDGES;
    __syncthreads();

    for (int i = tid; i < total; i += 1024) {
        unsigned int e;
        if (fits) e = sedge[i];
        else {
            int lo = 0, hi = NBLK - 1;
            while (lo < hi) { int mid = (lo + hi + 1) >> 1; if (rloff[mid] <= i) lo = mid; else hi = mid - 1; }
            e = esort[rpos[lo] + (i - rloff[lo])];
        }
        int r = (int)(e & 7u);
        int j = (int)((e >> 3) & 255u) * 8 + r;
        int p = atomicAdd(&cur[j], 1);
        unsigned int eo = (e >> 11) * WCOLS + (unsigned int)(r * 64);
        if (fits) selist[p] = eo;
        else      elist[seg0 + p] = eo;
    }
    __syncthreads();

    if (fits) {
        for (int i = tid; i < total; i += 1024)
            elist[seg0 + i] = selist[i];
    }
}

// ---------------- gemm_l1: xW[N][576] = x[N][128] @ BT1, dbuf B --------------
// 512 thr (8 waves, 128 rows/block). Double-buffered B: prefetch chunk c+1
// before MFMAs on chunk c, ONE barrier per chunk (was 2), half the blocks.
__global__ __launch_bounds__(512)
void gemm_l1(const float* __restrict__ A,
             const unsigned short* __restrict__ BT,
             unsigned short* __restrict__ Out, int nrows) {
    constexpr int K = C_IN;             // 128
    constexpr int LDB = K + 8;          // 136 (16B-aligned rows, 2-way banks = free)
    __shared__ __align__(16) unsigned short Blds[2][64 * LDB];  // 34.8 KB
    __shared__ __align__(16) unsigned short stage[8][16 * 64];  // 16 KB

    const int wave = threadIdx.x >> 6, lane = threadIdx.x & 63;
    const int l15 = lane & 15, quad = lane >> 4;
    const int rowbase = blockIdx.x * 128 + wave * 16;
    int arow = rowbase + l15;
    if (arow >= nrows) arow = nrows - 1;

    short8 afrag[4];
#pragma unroll
    for (int ks = 0; ks < 4; ++ks) {
        const float* p = A + (size_t)arow * K + ks * 32 + quad * 8;
        float4v u0 = *(const float4v*)p;
        float4v u1 = *(const float4v*)(p + 4);
        short8 f;
        f[0] = (short)f2bf(u0[0]); f[1] = (short)f2bf(u0[1]);
        f[2] = (short)f2bf(u0[2]); f[3] = (short)f2bf(u0[3]);
        f[4] = (short)f2bf(u1[0]); f[5] = (short)f2bf(u1[1]);
        f[6] = (short)f2bf(u1[2]); f[7] = (short)f2bf(u1[3]);
        afrag[ks] = f;
    }

    // preload chunk 0 into buf 0
    for (int i = threadIdx.x; i < 1024; i += 512) {
        int r = i >> 4, c = (i & 15) * 8;
        *(uint4*)&Blds[0][r * LDB + c] = *(const uint4*)(BT + r * K + c);
    }
    __syncthreads();

    int cur = 0;
    for (int chunk = 0; chunk < 9; ++chunk) {
        // issue next-chunk loads early (latency hides under MFMAs)
        uint4 p0, p1;
        const int i0 = threadIdx.x, i1 = threadIdx.x + 512;
        if (chunk < 8) {
            const unsigned short* src = BT + (size_t)(chunk + 1) * 64 * K;
            p0 = *(const uint4*)(src + (i0 >> 4) * K + (i0 & 15) * 8);
            p1 = *(const uint4*)(src + (i1 >> 4) * K + (i1 & 15) * 8);
        }

        float4v acc[4];
#pragma unroll
        for (int ct = 0; ct < 4; ++ct) { acc[ct][0] = 0.f; acc[ct][1] = 0.f; acc[ct][2] = 0.f; acc[ct][3] = 0.f; }
#pragma unroll
        for (int ct = 0; ct < 4; ++ct)
#pragma unroll
            for (int ks = 0; ks < 4; ++ks) {
                short8 bfrag = *(const short8*)(&Blds[cur][(ct * 16 + l15) * LDB + ks * 32 + quad * 8]);
                acc[ct] = __builtin_amdgcn_mfma_f32_16x16x32_bf16(afrag[ks], bfrag, acc[ct], 0, 0, 0);
            }

        // per-wave stage (same-wave LDS dep, no barrier) + coalesced store
#pragma unroll
        for (int ct = 0; ct < 4; ++ct)
#pragma unroll
            for (int r = 0; r < 4; ++r)
                stage[wave][(quad * 4 + r) * 64 + ct * 16 + l15] = f2bf(acc[ct][r]);
        {
            int r = lane >> 2, j = lane & 3;
            int orow = rowbase + r;
            if (orow < nrows) {
#pragma unroll
                for (int p = 0; p < 2; ++p) {
                    int c0 = (j + p * 4) * 8;
                    uint4 v = *(const uint4*)&stage[wave][r * 64 + c0];
                    *(uint4*)(Out + (size_t)orow * WCOLS + chunk * 64 + c0) = v;
                }
            }
        }

        if (chunk < 8) {     // write prefetched chunk into the other buffer
            *(uint4*)&Blds[cur ^ 1][(i0 >> 4) * LDB + (i0 & 15) * 8] = p0;
            *(uint4*)&Blds[cur ^ 1][(i1 >> 4) * LDB + (i1 & 15) * 8] = p1;
            cur ^= 1;
        }
        __syncthreads();     // next-chunk buffer complete before its MFMAs
    }
}

// ---------------- gemm_l2: hW[N][576] = h[N][64] @ BT2, B fully LDS-resident -
// B = 576x64 bf16 = 73.7 KB -> loaded ONCE; zero barriers in the row loop.
__global__ __launch_bounds__(512)
void gemm_l2(const unsigned short* __restrict__ A,     // h [N][64]
             const unsigned short* __restrict__ BT,    // [576][64]
             unsigned short* __restrict__ Out, int nrows) {
    constexpr int K = HID;              // 64
    constexpr int LDB = K + 8;          // 72
    __shared__ __align__(16) unsigned short Blds[WCOLS * LDB];   // 82.9 KB
    __shared__ __align__(16) unsigned short stage[8][16 * 64];   // 16 KB

    const int wave = threadIdx.x >> 6, lane = threadIdx.x & 63;
    const int l15 = lane & 15, quad = lane >> 4;

    for (int i = threadIdx.x; i < WCOLS * K / 8; i += 512) {     // 4608
        int c = i >> 3, kv = (i & 7) * 8;
        *(uint4*)&Blds[c * LDB + kv] = *(const uint4*)(BT + c * K + kv);
    }
    __syncthreads();    // the only barrier

    const int ntiles = (nrows + 127) / 128;
    for (int t = blockIdx.x; t < ntiles; t += gridDim.x) {
        const int rowbase = t * 128 + wave * 16;
        int arow = rowbase + l15;
        if (arow >= nrows) arow = nrows - 1;
        short8 afrag[2];
#pragma unroll
        for (int ks = 0; ks < 2; ++ks)
            afrag[ks] = *(const short8*)(A + (size_t)arow * K + ks * 32 + quad * 8);

        for (int chunk = 0; chunk < 9; ++chunk) {
            float4v acc[4];
#pragma unroll
            for (int ct = 0; ct < 4; ++ct) { acc[ct][0] = 0.f; acc[ct][1] = 0.f; acc[ct][2] = 0.f; acc[ct][3] = 0.f; }
#pragma unroll
            for (int ct = 0; ct < 4; ++ct)
#pragma unroll
                for (int ks = 0; ks < 2; ++ks) {
                    short8 bfrag = *(const short8*)(&Blds[(chunk * 64 + ct * 16 + l15) * LDB + ks * 32 + quad * 8]);
                    acc[ct] = __builtin_amdgcn_mfma_f32_16x16x32_bf16(afrag[ks], bfrag, acc[ct], 0, 0, 0);
                }

#pragma unroll
            for (int ct = 0; ct < 4; ++ct)
#pragma unroll
                for (int r = 0; r < 4; ++r)
                    stage[wave][(quad * 4 + r) * 64 + ct * 16 + l15] = f2bf(acc[ct][r]);
            {
                int r = lane >> 2, j = lane & 3;
                int orow = rowbase + r;
                if (orow < nrows) {
#pragma unroll
                    for (int p = 0; p < 2; ++p) {
                        int c0 = (j + p * 4) * 8;
                        uint4 v = *(const uint4*)&stage[wave][r * 64 + c0];
                        *(uint4*)(Out + (size_t)orow * WCOLS + chunk * 64 + c0) = v;
                    }
                }
            }
        }
    }
}

// ---------------- fused CSR aggregate + root + bias (+relu) ------------------
template <int MODE>   // 0: relu -> bf16 h ; 1: -> f32 out
__global__ __launch_bounds__(256)
void agg_fused(const unsigned short* __restrict__ XW,
               const unsigned int* __restrict__ elist,
               const int* __restrict__ rowstart8,
               const float* __restrict__ bias,
               void* __restrict__ outp) {
    const int wave = threadIdx.x >> 6, lane = threadIdx.x & 63;
    const int n = blockIdx.x * 4 + wave;          // grid covers N exactly
    int r9 = 0;
    if (lane < 9) r9 = rowstart8[n * 8 + lane];
    const int b0 = __builtin_amdgcn_readlane(r9, 0);
    const int b1 = __builtin_amdgcn_readlane(r9, 1);
    const int b2 = __builtin_amdgcn_readlane(r9, 2);
    const int b3 = __builtin_amdgcn_readlane(r9, 3);
    const int b4 = __builtin_amdgcn_readlane(r9, 4);
    const int b5 = __builtin_amdgcn_readlane(r9, 5);
    const int b6 = __builtin_amdgcn_readlane(r9, 6);
    const int b7 = __builtin_amdgcn_readlane(r9, 7);
    const int b8 = __builtin_amdgcn_readlane(r9, 8);
    const int beg = b0, end = b8;

    auto invlen = [](int a, int bnd) {
        int l = bnd - a; return 1.0f / (float)(l > 1 ? l : 1);
    };
    const float il0 = invlen(b0, b1), il1 = invlen(b1, b2);
    const float il2 = invlen(b2, b3), il3 = invlen(b3, b4);
    const float il4 = invlen(b4, b5), il5 = invlen(b5, b6);
    const float il6 = invlen(b6, b7), il7 = invlen(b7, b8);

    const unsigned short* XWl = XW + lane;        // fold lane offset into base

    float acc = 0.f;
    int i = beg;
    while (i < end) {
        int m = end - i; if (m > 64) m = 64;
        int idx = i + lane; if (idx >= end) idx = end - 1;
        unsigned int ub = elist[idx];             // offset (coalesced, 1 load / 64 edges)
        float wb = il0;
        wb = (idx >= b1) ? il1 : wb;
        wb = (idx >= b2) ? il2 : wb;
        wb = (idx >= b3) ? il3 : wb;
        wb = (idx >= b4) ? il4 : wb;
        wb = (idx >= b5) ? il5 : wb;
        wb = (idx >= b6) ? il6 : wb;
        wb = (idx >= b7) ? il7 : wb;

        int j = 0;
        for (; j + 16 <= m; j += 16) {
            float vv[16], ww[16];
#pragma unroll
            for (int t = 0; t < 16; ++t) {
                unsigned int u = (unsigned int)__builtin_amdgcn_readlane((int)ub, j + t);
                ww[t] = rl_f(wb, j + t);
                vv[t] = bf2f(XWl[u]);
            }
#pragma unroll
            for (int t = 0; t < 16; ++t) acc += ww[t] * vv[t];
        }
        for (; j + 4 <= m; j += 4) {
            float vv[4], ww[4];
#pragma unroll
            for (int t = 0; t < 4; ++t) {
                unsigned int u = (unsigned int)__builtin_amdgcn_readlane((int)ub, j + t);
                ww[t] = rl_f(wb, j + t);
                vv[t] = bf2f(XWl[u]);
            }
#pragma unroll
            for (int t = 0; t < 4; ++t) acc += ww[t] * vv[t];
        }
        for (; j < m; ++j) {
            unsigned int u = (unsigned int)__builtin_amdgcn_readlane((int)ub, j);
            float w = rl_f(wb, j);
            acc += w * bf2f(XWl[u]);
        }
        i += m;
    }

    float res = acc + bf2f(XW[(size_t)n * WCOLS + 512 + lane]) + bias[lane];
    if (MODE == 0) {
        res = res > 0.f ? res : 0.f;
        ((unsigned short*)outp)[(size_t)n * 64 + lane] = f2bf(res);
    } else {
        ((float*)outp)[(size_t)n * 64 + lane] = res;
    }
}

// ---------------- launch ------------------------------------------------------
extern "C" void kernel_launch(void* const* d_in, const int* in_sizes, int n_in,
                              void* d_out, int out_size, void* d_ws, size_t ws_size,
                              hipStream_t stream) {
    const float* x     = (const float*)d_in[0];
    const int*   eidx  = (const int*)d_in[1];
    const int*   etyp  = (const int*)d_in[2];
    const float* W1    = (const float*)d_in[3];
    const float* root1 = (const float*)d_in[4];
    const float* b1    = (const float*)d_in[5];
    const float* W2    = (const float*)d_in[6];
    const float* root2 = (const float*)d_in[7];
    const float* b2    = (const float*)d_in[8];
    float*       out   = (float*)d_out;

    char* ws = (char*)d_ws;
    size_t off = 0;
    auto alloc = [&](size_t bytes) { char* p = ws + off; off += (bytes + 255) & ~(size_t)255; return p; };

    unsigned short* xW       = (unsigned short*)alloc((size_t)N_NODES * WCOLS * 2); // 115.2 MB (reused as hW)
    unsigned short* h        = (unsigned short*)alloc((size_t)N_NODES * HID * 2);   //  12.8 MB
    unsigned int*   elist    = (unsigned int*)alloc((size_t)N_EDGES * 4);           //  12.8 MB
    int*            rowstart8= (int*)alloc(((size_t)N_NODES * 8 + 1) * 4);          //   3.2 MB
    unsigned short* BT1      = (unsigned short*)alloc((size_t)WCOLS * C_IN * 2);
    unsigned short* BT2      = (unsigned short*)alloc((size_t)WCOLS * HID * 2);
    // total ~144.5 MB

    // sort scratch aliases into xW (dead before gemm1 writes xW)
    unsigned int* esort   = (unsigned int*)xW;                          // 12.8 MB
    int*          bcountT = (int*)((char*)xW + (size_t)N_EDGES * 4);    //  0.5 MB
    int*          lstartT = bcountT + NCELL;                            //  0.5 MB

    const int* srcp = eidx;
    const int* dstp = eidx + N_EDGES;

    prep_wcat<<<(WCOLS * (C_IN + HID) + 255) / 256, 256, 0, stream>>>(W1, root1, W2, root2, BT1, BT2);

    // CSR build — sequential-write sort + fused per-bucket CSR emit
    edge_sort_local<<<NBLK, 1024, 0, stream>>>(srcp, dstp, etyp, esort, bcountT, lstartT);
    bucket_build<<<NBUCK, 1024, 0, stream>>>(esort, bcountT, lstartT, elist, rowstart8);

    const int gemm1_grid = (N_NODES + 127) / 128;  // 782
    const int agg_grid   = N_NODES / 4;            // 25000

    // layer 1: x (f32) -> xW (bf16) -> h (bf16, relu)
    gemm_l1<<<gemm1_grid, 512, 0, stream>>>(x, BT1, xW, N_NODES);
    agg_fused<0><<<agg_grid, 256, 0, stream>>>(xW, elist, rowstart8, b1, (void*)h);

    // layer 2: h -> hW (reuse xW) -> out (f32)
    gemm_l2<<<256, 512, 0, stream>>>(h, BT2, xW, N_NODES);
    agg_fused<1><<<agg_grid, 256, 0, stream>>>(xW, elist, rowstart8, b2, (void*)out);
}

// Round 8
// 367.049 us; speedup vs baseline: 1.3681x; 1.0325x over previous
//
#include <hip/hip_runtime.h>

#define N_NODES 100000
#define N_EDGES 3200000
#define R_REL   8
#define C_IN    128
#define HID     64
#define WCOLS   576   // 8 relations * 64 + 64 (root slot)

// counting-sort parameters
#define NBUCK 500     // dst buckets
#define NPB   200     // nodes per bucket (500*200 = N)
#define NBLK  256     // edge chunks (runs: CHUNK/NBUCK = 25 edges = 100 B)
#define CHUNK 12500   // E / NBLK (exact)
#define NCELL (NBUCK * NBLK)   // 128000
#define BCAP  7424    // LDS staging cap (mean 6400, sigma ~80 -> +12.8 sigma; keeps LDS<80KB for 2 blocks/CU)
#define PREPC 432     // prep elems per sort block (256*432 = 110592 = WCOLS*(C_IN+HID))

typedef __attribute__((ext_vector_type(8))) short  short8;
typedef __attribute__((ext_vector_type(4))) float  float4v;

__device__ __forceinline__ float bf2f(unsigned short u) {
    union { unsigned int i; float f; } v; v.i = ((unsigned int)u) << 16; return v.f;
}
__device__ __forceinline__ unsigned short f2bf(float f) {
    union { float f; unsigned int i; } v; v.f = f;
    unsigned int r = v.i + 0x7FFFu + ((v.i >> 16) & 1u);   // RNE
    return (unsigned short)(r >> 16);
}
__device__ __forceinline__ float rl_f(float v, int j) {
    union { float f; int i; } a, b; a.f = v;
    b.i = __builtin_amdgcn_readlane(a.i, j);
    return b.f;
}

// exclusive scan of v across 1024 threads via shfl wave-scans (3 barriers).
// wsum: shared int[16]. Returns exclusive prefix; *tot (optional) = total.
__device__ __forceinline__ int block_exscan_1024(int v, int tid, int* wsum, int* tot) {
    __syncthreads();                       // protect wsum reuse
    const int lane = tid & 63, wid = tid >> 6;
    int s = v;
#pragma unroll
    for (int d = 1; d < 64; d <<= 1) {
        int t = __shfl_up(s, d, 64);
        if (lane >= d) s += t;
    }
    if (lane == 63) wsum[wid] = s;
    __syncthreads();
    if (wid == 0) {
        int ws = (lane < 16) ? wsum[lane] : 0;
#pragma unroll
        for (int d = 1; d < 16; d <<= 1) {
            int t = __shfl_up(ws, d, 64);
            if (lane >= d) ws += t;
        }
        if (lane < 16) wsum[lane] = ws;    // inclusive wave partials
    }
    __syncthreads();
    int wexcl = (wid == 0) ? 0 : wsum[wid - 1];
    if (tot) *tot = wsum[15];
    return wexcl + s - v;
}

// ---------------- K1: per-block LDS counting sort (+ folded weight prep) -----
// esort[blk*CHUNK...] = block's edges sorted by bucket (packed src<<11|dl<<3|rel)
// bcountT[blk*NBUCK+b] = count; lstartT[blk*NBUCK+b] = local exclusive prefix.
__global__ __launch_bounds__(1024)
void edge_sort_local(const int* __restrict__ src, const int* __restrict__ dst,
                     const int* __restrict__ et,
                     const float* __restrict__ W1, const float* __restrict__ root1,
                     const float* __restrict__ W2, const float* __restrict__ root2,
                     unsigned short* __restrict__ BT1, unsigned short* __restrict__ BT2,
                     unsigned int* __restrict__ esort,
                     int* __restrict__ bcountT, int* __restrict__ lstartT) {
    __shared__ int cnt[NBUCK], cur[NBUCK], wsum[16];
    __shared__ unsigned int sedge[CHUNK];               // 50 KB
    const int blk = blockIdx.x, tid = threadIdx.x;
    const int e0 = blk * CHUNK;

    // folded weight prep: 432 elems per block, exact cover of 110592
    if (tid < PREPC) {
        int idx = blk * PREPC + tid;
        const int T1 = WCOLS * C_IN;          // 73728
        if (idx < T1) {
            int c = idx / C_IN, k = idx % C_IN;
            float v;
            if (c < 512) { int r = c >> 6, h = c & 63; v = W1[r * (C_IN * 64) + k * 64 + h]; }
            else         { v = root1[k * 64 + (c - 512)]; }
            BT1[idx] = f2bf(v);
        } else {
            int j = idx - T1;
            int c = j / HID, k = j % HID;
            float v;
            if (c < 512) { int r = c >> 6, h = c & 63; v = W2[r * (HID * 64) + k * 64 + h]; }
            else         { v = root2[k * 64 + (c - 512)]; }
            BT2[j] = f2bf(v);
        }
    }

    for (int i = tid; i < NBUCK; i += 1024) cnt[i] = 0;
    __syncthreads();
    for (int i = tid; i < CHUNK; i += 1024)
        atomicAdd(&cnt[dst[e0 + i] / NPB], 1);
    __syncthreads();

    int v = (tid < NBUCK) ? cnt[tid] : 0;
    int ex = block_exscan_1024(v, tid, wsum, nullptr);
    if (tid < NBUCK) {
        cur[tid] = ex;
        bcountT[blk * NBUCK + tid] = v;
        lstartT[blk * NBUCK + tid] = ex;
    }
    __syncthreads();     // cur stable before scatter atomics

    for (int i = tid; i < CHUNK; i += 1024) {
        int d = dst[e0 + i];
        int b = d / NPB;
        int pos = atomicAdd(&cur[b], 1);
        sedge[pos] = ((unsigned int)src[e0 + i] << 11) |
                     ((unsigned int)(d - b * NPB) << 3) | (unsigned int)et[e0 + i];
    }
    __syncthreads();
    for (int i = tid; i < CHUNK; i += 1024) esort[e0 + i] = sedge[i];
}

// ---------------- bucket_build v6: 2 blocks/CU, search-free, wave scans ------
// one block per bucket, 1024 threads, ~77 KB LDS (2 blocks/CU -> grid of 500
// runs in ONE round over 256 CUs instead of two).
// pass 1: 4 threads per run (256 runs) — no binary search; stage + histogram.
// pass 2: flat over staged LDS (or run-assigned fallback if total > BCAP).
__global__ __launch_bounds__(1024)
void bucket_build(const unsigned int* __restrict__ esort,
                  const int* __restrict__ bcountT, const int* __restrict__ lstartT,
                  unsigned int* __restrict__ elist,
                  int* __restrict__ rowstart8) {
    __shared__ int   cnt[2048], cur[2048];              // 16384 B
    __shared__ int   rlen_s[NBLK], rpos[NBLK], rloff[NBLK], wsum[16];  // 3136 B
    __shared__ unsigned int sedge[BCAP];                // 29696 B
    __shared__ unsigned int selist[BCAP];               // 29696 B  (total ~77 KB)

    const int b = blockIdx.x, tid = threadIdx.x;

    for (int i = tid; i < 2048; i += 1024) cnt[i] = 0;
    int myrl = 0, myls = 0;
    if (tid < NBLK) {
        myrl = bcountT[tid * NBUCK + b];
        myls = lstartT[tid * NBUCK + b];
        rlen_s[tid] = myrl;
        rpos[tid] = tid * CHUNK + myls;
    }

    int total;
    int rex = block_exscan_1024(myrl, tid, wsum, &total);   // entries >=NBLK are 0
    if (tid < NBLK) rloff[tid] = rex;

    // seg0 = sum of per-block local prefixes == global exclusive prefix of b
    int seg0;
    (void)block_exscan_1024(myls, tid, wsum, &seg0);
    __syncthreads();                     // rloff/rlen_s/rpos visible
    const bool fits = (total <= BCAP);   // safety fallback

    // ---- pass 1: run-assigned (4 thr/run), stage + histogram, no search ----
    {
        const int run = tid >> 2, sub = tid & 3;
        const int len = rlen_s[run], lp = rpos[run], ro = rloff[run];
        for (int k = sub; k < len; k += 4) {
            unsigned int e = esort[lp + k];
            if (fits) sedge[ro + k] = e;
            atomicAdd(&cnt[(int)((e >> 3) & 255u) * 8 + (int)(e & 7u)], 1);
        }
    }
    __syncthreads();

    // ---- exclusive scan over 2048 counters: 2/thread + wave scan ----
    int base = tid * 2;
    int c0 = cnt[base], c1 = cnt[base + 1];
    int ex2 = block_exscan_1024(c0 + c1, tid, wsum, nullptr);
    cur[base] = ex2; cur[base + 1] = ex2 + c0;
    __syncthreads();

    // ---- per-(node,rel) boundary table ----
    for (int i = tid; i < NPB * 8; i += 1024)
        rowstart8[(b * NPB) * 8 + i] = seg0 + cur[i];
    if (b == NBUCK - 1 && tid == 0) rowstart8[N_NODES * 8] = N_EDGES;
    __syncthreads();                     // cur reads done before emit atomics

    // ---- pass 2: emit (scatter stays in LDS when fits) ----
    if (fits) {
        for (int i = tid; i < total; i += 1024) {
            unsigned int e = sedge[i];
            int r = (int)(e & 7u);
            int j = (int)((e >> 3) & 255u) * 8 + r;
            int p = atomicAdd(&cur[j], 1);
            selist[p] = (e >> 11) * WCOLS + (unsigned int)(r * 64);
        }
        __syncthreads();
        for (int i = tid; i < total; i += 1024)
            elist[seg0 + i] = selist[i];
    } else {
        const int run = tid >> 2, sub = tid & 3;
        const int len = rlen_s[run], lp = rpos[run];
        for (int k = sub; k < len; k += 4) {
            unsigned int e = esort[lp + k];
            int r = (int)(e & 7u);
            int j = (int)((e >> 3) & 255u) * 8 + r;
            int p = atomicAdd(&cur[j], 1);
            elist[seg0 + p] = (e >> 11) * WCOLS + (unsigned int)(r * 64);
        }
    }
}

// ---------------- gemm_l1: xW[N][576] = x[N][128] @ BT1, dbuf B --------------
__global__ __launch_bounds__(512)
void gemm_l1(const float* __restrict__ A,
             const unsigned short* __restrict__ BT,
             unsigned short* __restrict__ Out, int nrows) {
    constexpr int K = C_IN;             // 128
    constexpr int LDB = K + 8;          // 136
    __shared__ __align__(16) unsigned short Blds[2][64 * LDB];  // 34.8 KB
    __shared__ __align__(16) unsigned short stage[8][16 * 64];  // 16 KB

    const int wave = threadIdx.x >> 6, lane = threadIdx.x & 63;
    const int l15 = lane & 15, quad = lane >> 4;
    const int rowbase = blockIdx.x * 128 + wave * 16;
    int arow = rowbase + l15;
    if (arow >= nrows) arow = nrows - 1;

    short8 afrag[4];
#pragma unroll
    for (int ks = 0; ks < 4; ++ks) {
        const float* p = A + (size_t)arow * K + ks * 32 + quad * 8;
        float4v u0 = *(const float4v*)p;
        float4v u1 = *(const float4v*)(p + 4);
        short8 f;
        f[0] = (short)f2bf(u0[0]); f[1] = (short)f2bf(u0[1]);
        f[2] = (short)f2bf(u0[2]); f[3] = (short)f2bf(u0[3]);
        f[4] = (short)f2bf(u1[0]); f[5] = (short)f2bf(u1[1]);
        f[6] = (short)f2bf(u1[2]); f[7] = (short)f2bf(u1[3]);
        afrag[ks] = f;
    }

    for (int i = threadIdx.x; i < 1024; i += 512) {
        int r = i >> 4, c = (i & 15) * 8;
        *(uint4*)&Blds[0][r * LDB + c] = *(const uint4*)(BT + r * K + c);
    }
    __syncthreads();

    int cur = 0;
    for (int chunk = 0; chunk < 9; ++chunk) {
        uint4 p0, p1;
        const int i0 = threadIdx.x, i1 = threadIdx.x + 512;
        if (chunk < 8) {
            const unsigned short* src = BT + (size_t)(chunk + 1) * 64 * K;
            p0 = *(const uint4*)(src + (i0 >> 4) * K + (i0 & 15) * 8);
            p1 = *(const uint4*)(src + (i1 >> 4) * K + (i1 & 15) * 8);
        }

        float4v acc[4];
#pragma unroll
        for (int ct = 0; ct < 4; ++ct) { acc[ct][0] = 0.f; acc[ct][1] = 0.f; acc[ct][2] = 0.f; acc[ct][3] = 0.f; }
#pragma unroll
        for (int ct = 0; ct < 4; ++ct)
#pragma unroll
            for (int ks = 0; ks < 4; ++ks) {
                short8 bfrag = *(const short8*)(&Blds[cur][(ct * 16 + l15) * LDB + ks * 32 + quad * 8]);
                acc[ct] = __builtin_amdgcn_mfma_f32_16x16x32_bf16(afrag[ks], bfrag, acc[ct], 0, 0, 0);
            }

#pragma unroll
        for (int ct = 0; ct < 4; ++ct)
#pragma unroll
            for (int r = 0; r < 4; ++r)
                stage[wave][(quad * 4 + r) * 64 + ct * 16 + l15] = f2bf(acc[ct][r]);
        {
            int r = lane >> 2, j = lane & 3;
            int orow = rowbase + r;
            if (orow < nrows) {
#pragma unroll
                for (int p = 0; p < 2; ++p) {
                    int c0 = (j + p * 4) * 8;
                    uint4 v = *(const uint4*)&stage[wave][r * 64 + c0];
                    *(uint4*)(Out + (size_t)orow * WCOLS + chunk * 64 + c0) = v;
                }
            }
        }

        if (chunk < 8) {
            *(uint4*)&Blds[cur ^ 1][(i0 >> 4) * LDB + (i0 & 15) * 8] = p0;
            *(uint4*)&Blds[cur ^ 1][(i1 >> 4) * LDB + (i1 & 15) * 8] = p1;
            cur ^= 1;
        }
        __syncthreads();
    }
}

// ---------------- gemm_l2: hW[N][576] = h[N][64] @ BT2, B fully LDS-resident -
__global__ __launch_bounds__(512)
void gemm_l2(const unsigned short* __restrict__ A,     // h [N][64]
             const unsigned short* __restrict__ BT,    // [576][64]
             unsigned short* __restrict__ Out, int nrows) {
    constexpr int K = HID;              // 64
    constexpr int LDB = K + 8;          // 72
    __shared__ __align__(16) unsigned short Blds[WCOLS * LDB];   // 82.9 KB
    __shared__ __align__(16) unsigned short stage[8][16 * 64];   // 16 KB

    const int wave = threadIdx.x >> 6, lane = threadIdx.x & 63;
    const int l15 = lane & 15, quad = lane >> 4;

    for (int i = threadIdx.x; i < WCOLS * K / 8; i += 512) {
        int c = i >> 3, kv = (i & 7) * 8;
        *(uint4*)&Blds[c * LDB + kv] = *(const uint4*)(BT + c * K + kv);
    }
    __syncthreads();    // the only barrier

    const int ntiles = (nrows + 127) / 128;
    for (int t = blockIdx.x; t < ntiles; t += gridDim.x) {
        const int rowbase = t * 128 + wave * 16;
        int arow = rowbase + l15;
        if (arow >= nrows) arow = nrows - 1;
        short8 afrag[2];
#pragma unroll
        for (int ks = 0; ks < 2; ++ks)
            afrag[ks] = *(const short8*)(A + (size_t)arow * K + ks * 32 + quad * 8);

        for (int chunk = 0; chunk < 9; ++chunk) {
            float4v acc[4];
#pragma unroll
            for (int ct = 0; ct < 4; ++ct) { acc[ct][0] = 0.f; acc[ct][1] = 0.f; acc[ct][2] = 0.f; acc[ct][3] = 0.f; }
#pragma unroll
            for (int ct = 0; ct < 4; ++ct)
#pragma unroll
                for (int ks = 0; ks < 2; ++ks) {
                    short8 bfrag = *(const short8*)(&Blds[(chunk * 64 + ct * 16 + l15) * LDB + ks * 32 + quad * 8]);
                    acc[ct] = __builtin_amdgcn_mfma_f32_16x16x32_bf16(afrag[ks], bfrag, acc[ct], 0, 0, 0);
                }

#pragma unroll
            for (int ct = 0; ct < 4; ++ct)
#pragma unroll
                for (int r = 0; r < 4; ++r)
                    stage[wave][(quad * 4 + r) * 64 + ct * 16 + l15] = f2bf(acc[ct][r]);
            {
                int r = lane >> 2, j = lane & 3;
                int orow = rowbase + r;
                if (orow < nrows) {
#pragma unroll
                    for (int p = 0; p < 2; ++p) {
                        int c0 = (j + p * 4) * 8;
                        uint4 v = *(const uint4*)&stage[wave][r * 64 + c0];
                        *(uint4*)(Out + (size_t)orow * WCOLS + chunk * 64 + c0) = v;
                    }
                }
            }
        }
    }
}

// ---------------- fused CSR aggregate + root + bias (+relu) ------------------
template <int MODE>   // 0: relu -> bf16 h ; 1: -> f32 out
__global__ __launch_bounds__(256)
void agg_fused(const unsigned short* __restrict__ XW,
               const unsigned int* __restrict__ elist,
               const int* __restrict__ rowstart8,
               const float* __restrict__ bias,
               void* __restrict__ outp) {
    const int wave = threadIdx.x >> 6, lane = threadIdx.x & 63;
    const int n = blockIdx.x * 4 + wave;          // grid covers N exactly
    int r9 = 0;
    if (lane < 9) r9 = rowstart8[n * 8 + lane];
    const int b0 = __builtin_amdgcn_readlane(r9, 0);
    const int b1 = __builtin_amdgcn_readlane(r9, 1);
    const int b2 = __builtin_amdgcn_readlane(r9, 2);
    const int b3 = __builtin_amdgcn_readlane(r9, 3);
    const int b4 = __builtin_amdgcn_readlane(r9, 4);
    const int b5 = __builtin_amdgcn_readlane(r9, 5);
    const int b6 = __builtin_amdgcn_readlane(r9, 6);
    const int b7 = __builtin_amdgcn_readlane(r9, 7);
    const int b8 = __builtin_amdgcn_readlane(r9, 8);
    const int beg = b0, end = b8;

    auto invlen = [](int a, int bnd) {
        int l = bnd - a; return 1.0f / (float)(l > 1 ? l : 1);
    };
    const float il0 = invlen(b0, b1), il1 = invlen(b1, b2);
    const float il2 = invlen(b2, b3), il3 = invlen(b3, b4);
    const float il4 = invlen(b4, b5), il5 = invlen(b5, b6);
    const float il6 = invlen(b6, b7), il7 = invlen(b7, b8);

    const unsigned short* XWl = XW + lane;        // fold lane offset into base

    float acc = 0.f;
    int i = beg;
    while (i < end) {
        int m = end - i; if (m > 64) m = 64;
        int idx = i + lane; if (idx >= end) idx = end - 1;
        unsigned int ub = elist[idx];             // offset (coalesced, 1 load / 64 edges)
        float wb = il0;
        wb = (idx >= b1) ? il1 : wb;
        wb = (idx >= b2) ? il2 : wb;
        wb = (idx >= b3) ? il3 : wb;
        wb = (idx >= b4) ? il4 : wb;
        wb = (idx >= b5) ? il5 : wb;
        wb = (idx >= b6) ? il6 : wb;
        wb = (idx >= b7) ? il7 : wb;

        int j = 0;
        for (; j + 16 <= m; j += 16) {
            float vv[16], ww[16];
#pragma unroll
            for (int t = 0; t < 16; ++t) {
                unsigned int u = (unsigned int)__builtin_amdgcn_readlane((int)ub, j + t);
                ww[t] = rl_f(wb, j + t);
                vv[t] = bf2f(XWl[u]);
            }
#pragma unroll
            for (int t = 0; t < 16; ++t) acc += ww[t] * vv[t];
        }
        for (; j + 4 <= m; j += 4) {
            float vv[4], ww[4];
#pragma unroll
            for (int t = 0; t < 4; ++t) {
                unsigned int u = (unsigned int)__builtin_amdgcn_readlane((int)ub, j + t);
                ww[t] = rl_f(wb, j + t);
                vv[t] = bf2f(XWl[u]);
            }
#pragma unroll
            for (int t = 0; t < 4; ++t) acc += ww[t] * vv[t];
        }
        for (; j < m; ++j) {
            unsigned int u = (unsigned int)__builtin_amdgcn_readlane((int)ub, j);
            float w = rl_f(wb, j);
            acc += w * bf2f(XWl[u]);
        }
        i += m;
    }

    float res = acc + bf2f(XW[(size_t)n * WCOLS + 512 + lane]) + bias[lane];
    if (MODE == 0) {
        res = res > 0.f ? res : 0.f;
        ((unsigned short*)outp)[(size_t)n * 64 + lane] = f2bf(res);
    } else {
        ((float*)outp)[(size_t)n * 64 + lane] = res;
    }
}

// ---------------- launch ------------------------------------------------------
extern "C" void kernel_launch(void* const* d_in, const int* in_sizes, int n_in,
                              void* d_out, int out_size, void* d_ws, size_t ws_size,
                              hipStream_t stream) {
    const float* x     = (const float*)d_in[0];
    const int*   eidx  = (const int*)d_in[1];
    const int*   etyp  = (const int*)d_in[2];
    const float* W1    = (const float*)d_in[3];
    const float* root1 = (const float*)d_in[4];
    const float* b1    = (const float*)d_in[5];
    const float* W2    = (const float*)d_in[6];
    const float* root2 = (const float*)d_in[7];
    const float* b2    = (const float*)d_in[8];
    float*       out   = (float*)d_out;

    char* ws = (char*)d_ws;
    size_t off = 0;
    auto alloc = [&](size_t bytes) { char* p = ws + off; off += (bytes + 255) & ~(size_t)255; return p; };

    unsigned short* xW       = (unsigned short*)alloc((size_t)N_NODES * WCOLS * 2); // 115.2 MB (reused as hW)
    unsigned short* h        = (unsigned short*)alloc((size_t)N_NODES * HID * 2);   //  12.8 MB
    unsigned int*   elist    = (unsigned int*)alloc((size_t)N_EDGES * 4);           //  12.8 MB
    int*            rowstart8= (int*)alloc(((size_t)N_NODES * 8 + 1) * 4);          //   3.2 MB
    unsigned short* BT1      = (unsigned short*)alloc((size_t)WCOLS * C_IN * 2);
    unsigned short* BT2      = (unsigned short*)alloc((size_t)WCOLS * HID * 2);
    // total ~144.5 MB

    // sort scratch aliases into xW (dead before gemm_l1 writes xW)
    unsigned int* esort   = (unsigned int*)xW;                          // 12.8 MB
    int*          bcountT = (int*)((char*)xW + (size_t)N_EDGES * 4);    //  0.5 MB
    int*          lstartT = bcountT + NCELL;                            //  0.5 MB

    const int* srcp = eidx;
    const int* dstp = eidx + N_EDGES;

    // CSR build (weight prep folded into sort)
    edge_sort_local<<<NBLK, 1024, 0, stream>>>(srcp, dstp, etyp,
                                               W1, root1, W2, root2, BT1, BT2,
                                               esort, bcountT, lstartT);
    bucket_build<<<NBUCK, 1024, 0, stream>>>(esort, bcountT, lstartT, elist, rowstart8);

    const int gemm1_grid = (N_NODES + 127) / 128;  // 782
    const int agg_grid   = N_NODES / 4;            // 25000

    // layer 1: x (f32) -> xW (bf16) -> h (bf16, relu)
    gemm_l1<<<gemm1_grid, 512, 0, stream>>>(x, BT1, xW, N_NODES);
    agg_fused<0><<<agg_grid, 256, 0, stream>>>(xW, elist, rowstart8, b1, (void*)h);

    // layer 2: h -> hW (reuse xW) -> out (f32)
    gemm_l2<<<256, 512, 0, stream>>>(h, BT2, xW, N_NODES);
    agg_fused<1><<<agg_grid, 256, 0, stream>>>(xW, elist, rowstart8, b2, (void*)out);
}